// Round 1
// baseline (739.617 us; speedup 1.0000x reference)
//
#include <hip/hip_runtime.h>
#include <hip/hip_bf16.h>
#include <stdint.h>

typedef __attribute__((ext_vector_type(8))) short bf16x8;
typedef __attribute__((ext_vector_type(4))) float f32x4;

#define TOKENS 8192
#define DMODEL 1024
#define NQKV   3072
#define NSEQ   2048
#define NHEAD  16
#define DHEAD  64

__device__ __forceinline__ ushort f32_bf16(float f) {
    uint32_t u = __builtin_bit_cast(uint32_t, f);
    u = (u + 0x7fffu + ((u >> 16) & 1u)) >> 16;
    return (ushort)u;
}

// x [8192][1024] f32 -> bf16 (vectorized by 4)
__global__ void cvt_x_kernel(const float* __restrict__ x, ushort* __restrict__ xb) {
    int i = blockIdx.x * 256 + threadIdx.x;
    float4 v = reinterpret_cast<const float4*>(x)[i];
    ushort4 o;
    o.x = f32_bf16(v.x); o.y = f32_bf16(v.y);
    o.z = f32_bf16(v.z); o.w = f32_bf16(v.w);
    reinterpret_cast<ushort4*>(xb)[i] = o;
}

// w [1024][N] f32 -> wt [N][1024] bf16 (coalesced writes)
__global__ void cvt_wt_kernel(const float* __restrict__ w, ushort* __restrict__ wt, int N) {
    int i = blockIdx.x * 256 + threadIdx.x;   // i = n*1024 + k
    int k = i & 1023;
    int n = i >> 10;
    if (n < N) wt[i] = f32_bf16(w[(size_t)k * N + n]);
}

// C = A[M][1024] @ Bt[N][1024]^T, 128x128 block tile, 4 waves x 64x64.
// MODE 0: scatter to Q (scaled), K, V^T bf16 buffers. MODE 1: f32 out + bias.
template<int MODE>
__global__ __launch_bounds__(256) void gemm_bt(
    const ushort* __restrict__ A, const ushort* __restrict__ Bt,
    ushort* __restrict__ Qb, ushort* __restrict__ Kb, ushort* __restrict__ Vtb,
    float* __restrict__ Out, const float* __restrict__ bias)
{
    constexpr int K = 1024;
    const int lane = threadIdx.x & 63;
    const int w    = threadIdx.x >> 6;
    const int l16  = lane & 15;
    const int g    = lane >> 4;
    const int row0 = blockIdx.y * 128 + (w >> 1) * 64;
    const int col0 = blockIdx.x * 128 + (w & 1) * 64;

    f32x4 acc[4][4] = {};
    const ushort* Ap = A  + (size_t)(row0 + l16) * K + 8 * g;
    const ushort* Bp = Bt + (size_t)(col0 + l16) * K + 8 * g;

    for (int kk = 0; kk < K; kk += 32) {
        bf16x8 a[4], b[4];
        #pragma unroll
        for (int m = 0; m < 4; ++m)
            a[m] = *reinterpret_cast<const bf16x8*>(Ap + (size_t)(m * 16) * K + kk);
        #pragma unroll
        for (int n = 0; n < 4; ++n)
            b[n] = *reinterpret_cast<const bf16x8*>(Bp + (size_t)(n * 16) * K + kk);
        #pragma unroll
        for (int m = 0; m < 4; ++m)
            #pragma unroll
            for (int n = 0; n < 4; ++n)
                acc[m][n] = __builtin_amdgcn_mfma_f32_16x16x32_bf16(a[m], b[n], acc[m][n], 0, 0, 0);
    }

    if (MODE == 0) {
        const int part = col0 >> 10;                    // 0=Q 1=K 2=V (uniform per block)
        const float QSC = 0.18033688011112042f;         // DIM_HEAD^-0.5 * log2(e)
        #pragma unroll
        for (int m = 0; m < 4; ++m) {
            const int trow = row0 + m * 16 + 4 * g;
            #pragma unroll
            for (int n = 0; n < 4; ++n) {
                const int c  = col0 + n * 16 + l16;
                const int cc = c & 1023;
                const int h  = cc >> 6, d = cc & 63;
                #pragma unroll
                for (int jj = 0; jj < 4; ++jj) {
                    const int t  = trow + jj;
                    const int bb = t >> 11, nn = t & 2047;
                    const float v = acc[m][n][jj];
                    const size_t bhid = (size_t)(bb * NHEAD + h);
                    if (part == 0)
                        Qb[(bhid * NSEQ + nn) * DHEAD + d] = f32_bf16(v * QSC);
                    else if (part == 1)
                        Kb[(bhid * NSEQ + nn) * DHEAD + d] = f32_bf16(v);
                    else
                        Vtb[(bhid * DHEAD + d) * NSEQ + nn] = f32_bf16(v);
                }
            }
        }
    } else {
        #pragma unroll
        for (int m = 0; m < 4; ++m) {
            const int trow = row0 + m * 16 + 4 * g;
            #pragma unroll
            for (int n = 0; n < 4; ++n) {
                const int c = col0 + n * 16 + l16;
                const float bv = bias[c];
                #pragma unroll
                for (int jj = 0; jj < 4; ++jj)
                    Out[(size_t)(trow + jj) * DMODEL + c] = acc[m][n][jj] + bv;
            }
        }
    }
}

// Causal flash attention. Block: 4 waves, 64 q-rows (16/wave). Key tiles of 32.
// Q pre-scaled by SCALE*log2e -> exp2 softmax. P relayout via per-wave LDS.
__global__ __launch_bounds__(256) void attn_kernel(
    const ushort* __restrict__ Qb, const ushort* __restrict__ Kb,
    const ushort* __restrict__ Vtb, ushort* __restrict__ Ob)
{
    __shared__ __align__(16) ushort p_lds[4][16][40];   // pad stride 40 vs bank conflicts
    const int lane = threadIdx.x & 63;
    const int w    = threadIdx.x >> 6;
    const int l16  = lane & 15;
    const int g    = lane >> 4;
    const int bh   = blockIdx.y;                        // b*16 + h
    const int qr0  = blockIdx.x * 64 + w * 16;

    const ushort* Qp = Qb + ((size_t)bh * NSEQ + qr0 + l16) * DHEAD + 8 * g;
    const bf16x8 qf0 = *reinterpret_cast<const bf16x8*>(Qp);
    const bf16x8 qf1 = *reinterpret_cast<const bf16x8*>(Qp + 32);

    const ushort* Kp = Kb  + ((size_t)bh * NSEQ + l16) * DHEAD + 8 * g;
    const ushort* Vp = Vtb + ((size_t)bh * DHEAD + l16) * NSEQ + 8 * g;

    f32x4 oacc[4] = {};
    float mrow[4] = {-1e30f, -1e30f, -1e30f, -1e30f};
    float lrow[4] = {0.f, 0.f, 0.f, 0.f};

    const int kend = qr0 + 16;                          // causal: keys <= qr0+15
    for (int kt = 0; kt < kend; kt += 32) {
        f32x4 zero = {};
        const bf16x8 k0 = *reinterpret_cast<const bf16x8*>(Kp + (size_t)kt * DHEAD);
        const bf16x8 k1 = *reinterpret_cast<const bf16x8*>(Kp + (size_t)kt * DHEAD + 32);
        f32x4 s0 = __builtin_amdgcn_mfma_f32_16x16x32_bf16(qf0, k0, zero, 0, 0, 0);
        s0 = __builtin_amdgcn_mfma_f32_16x16x32_bf16(qf1, k1, s0, 0, 0, 0);
        const bf16x8 k2 = *reinterpret_cast<const bf16x8*>(Kp + (size_t)(kt + 16) * DHEAD);
        const bf16x8 k3 = *reinterpret_cast<const bf16x8*>(Kp + (size_t)(kt + 16) * DHEAD + 32);
        f32x4 s1 = __builtin_amdgcn_mfma_f32_16x16x32_bf16(qf0, k2, zero, 0, 0, 0);
        s1 = __builtin_amdgcn_mfma_f32_16x16x32_bf16(qf1, k3, s1, 0, 0, 0);

        const int key0 = kt + l16, key1 = key0 + 16;
        float ps[4];
        #pragma unroll
        for (int jj = 0; jj < 4; ++jj) {
            const int q = qr0 + 4 * g + jj;             // D-layout row for this reg
            const float a0 = (key0 <= q) ? s0[jj] : -1e30f;
            const float a1 = (key1 <= q) ? s1[jj] : -1e30f;
            float r = fmaxf(a0, a1);
            r = fmaxf(r, __shfl_xor(r, 1));
            r = fmaxf(r, __shfl_xor(r, 2));
            r = fmaxf(r, __shfl_xor(r, 4));
            r = fmaxf(r, __shfl_xor(r, 8));
            const float mn = fmaxf(mrow[jj], r);
            const float sc = __builtin_amdgcn_exp2f(mrow[jj] - mn);
            const float p0 = __builtin_amdgcn_exp2f(a0 - mn);
            const float p1 = __builtin_amdgcn_exp2f(a1 - mn);
            float psum = p0 + p1;
            psum += __shfl_xor(psum, 1);
            psum += __shfl_xor(psum, 2);
            psum += __shfl_xor(psum, 4);
            psum += __shfl_xor(psum, 8);
            lrow[jj] = lrow[jj] * sc + psum;
            mrow[jj] = mn;
            ps[jj] = sc;
            p_lds[w][4 * g + jj][l16]      = f32_bf16(p0);
            p_lds[w][4 * g + jj][16 + l16] = f32_bf16(p1);
        }
        #pragma unroll
        for (int dt = 0; dt < 4; ++dt)
            #pragma unroll
            for (int jj = 0; jj < 4; ++jj) oacc[dt][jj] *= ps[jj];

        asm volatile("s_waitcnt lgkmcnt(0)" ::: "memory");
        const bf16x8 pf = *reinterpret_cast<const bf16x8*>(&p_lds[w][l16][8 * g]);
        #pragma unroll
        for (int dt = 0; dt < 4; ++dt) {
            const bf16x8 vf = *reinterpret_cast<const bf16x8*>(Vp + (size_t)(dt * 16) * NSEQ + kt);
            oacc[dt] = __builtin_amdgcn_mfma_f32_16x16x32_bf16(pf, vf, oacc[dt], 0, 0, 0);
        }
    }

    const int bb = bh >> 4, h = bh & 15;
    #pragma unroll
    for (int jj = 0; jj < 4; ++jj) {
        const float inv = 1.0f / lrow[jj];
        const size_t t = (size_t)bb * NSEQ + qr0 + 4 * g + jj;
        #pragma unroll
        for (int dt = 0; dt < 4; ++dt)
            Ob[t * DMODEL + h * DHEAD + dt * 16 + l16] = f32_bf16(oacc[dt][jj] * inv);
    }
}

extern "C" void kernel_launch(void* const* d_in, const int* in_sizes, int n_in,
                              void* d_out, int out_size, void* d_ws, size_t ws_size,
                              hipStream_t stream)
{
    const float* x     = (const float*)d_in[0];
    const float* w_qkv = (const float*)d_in[1];
    const float* w_out = (const float*)d_in[2];
    const float* b_out = (const float*)d_in[3];
    float* out = (float*)d_out;

    char* ws = (char*)d_ws;
    // workspace layout (bytes); total 75,497,472
    ushort* x_bf   = (ushort*)(ws);                    // 16,777,216  (reused as attn out)
    ushort* wqkv_t = (ushort*)(ws + 16777216);         //  6,291,456
    ushort* wout_t = (ushort*)(ws + 23068672);         //  2,097,152
    ushort* q_bf   = (ushort*)(ws + 25165824);         // 16,777,216
    ushort* k_bf   = (ushort*)(ws + 41943040);         // 16,777,216
    ushort* vt_bf  = (ushort*)(ws + 58720256);         // 16,777,216
    ushort* attn_bf = x_bf;                            // alias: x_bf dead after QKV GEMM

    cvt_x_kernel<<<dim3(TOKENS * DMODEL / 4 / 256), dim3(256), 0, stream>>>(x, x_bf);
    cvt_wt_kernel<<<dim3(NQKV * 1024 / 256), dim3(256), 0, stream>>>(w_qkv, wqkv_t, NQKV);
    cvt_wt_kernel<<<dim3(1024 * 1024 / 256), dim3(256), 0, stream>>>(w_out, wout_t, 1024);

    gemm_bt<0><<<dim3(NQKV / 128, TOKENS / 128), dim3(256), 0, stream>>>(
        x_bf, wqkv_t, q_bf, k_bf, vt_bf, nullptr, nullptr);

    attn_kernel<<<dim3(NSEQ / 64, 64), dim3(256), 0, stream>>>(q_bf, k_bf, vt_bf, attn_bf);

    gemm_bt<1><<<dim3(DMODEL / 128, TOKENS / 128), dim3(256), 0, stream>>>(
        attn_bf, wout_t, nullptr, nullptr, nullptr, out, b_out);
}

// Round 2
// 738.860 us; speedup vs baseline: 1.0010x; 1.0010x over previous
//
#include <hip/hip_runtime.h>
#include <hip/hip_bf16.h>
#include <stdint.h>

typedef __attribute__((ext_vector_type(8))) short bf16x8;
typedef __attribute__((ext_vector_type(4))) float f32x4;

#define TOKENS 8192
#define DMODEL 1024
#define NQKV   3072
#define NSEQ   2048
#define NHEAD  16
#define DHEAD  64

__device__ __forceinline__ ushort f32_bf16(float f) {
    uint32_t u = __builtin_bit_cast(uint32_t, f);
    u = (u + 0x7fffu + ((u >> 16) & 1u)) >> 16;
    return (ushort)u;
}

// x [8192][1024] f32 -> bf16 (vectorized by 4)
__global__ void cvt_x_kernel(const float* __restrict__ x, ushort* __restrict__ xb) {
    int i = blockIdx.x * 256 + threadIdx.x;
    float4 v = reinterpret_cast<const float4*>(x)[i];
    ushort4 o;
    o.x = f32_bf16(v.x); o.y = f32_bf16(v.y);
    o.z = f32_bf16(v.z); o.w = f32_bf16(v.w);
    reinterpret_cast<ushort4*>(xb)[i] = o;
}

// w [1024][N] f32 -> wt [N][1024] bf16 (coalesced writes)
__global__ void cvt_wt_kernel(const float* __restrict__ w, ushort* __restrict__ wt, int N) {
    int i = blockIdx.x * 256 + threadIdx.x;   // i = n*1024 + k
    int k = i & 1023;
    int n = i >> 10;
    if (n < N) wt[i] = f32_bf16(w[(size_t)k * N + n]);
}

// C = A[M][1024] @ Bt[N][1024]^T, 128x128 block tile, 4 waves x 64x64.
// MODE 0: scatter to Q (scaled), K, V^T bf16 buffers. MODE 1: f32 out + bias.
template<int MODE>
__global__ __launch_bounds__(256) void gemm_bt(
    const ushort* __restrict__ A, const ushort* __restrict__ Bt,
    ushort* __restrict__ Qb, ushort* __restrict__ Kb, ushort* __restrict__ Vtb,
    float* __restrict__ Out, const float* __restrict__ bias)
{
    constexpr int K = 1024;
    const int lane = threadIdx.x & 63;
    const int w    = threadIdx.x >> 6;
    const int l16  = lane & 15;
    const int g    = lane >> 4;
    const int row0 = blockIdx.y * 128 + (w >> 1) * 64;
    const int col0 = blockIdx.x * 128 + (w & 1) * 64;

    f32x4 acc[4][4] = {};
    const ushort* Ap = A  + (size_t)(row0 + l16) * K + 8 * g;
    const ushort* Bp = Bt + (size_t)(col0 + l16) * K + 8 * g;

    for (int kk = 0; kk < K; kk += 32) {
        bf16x8 a[4], b[4];
        #pragma unroll
        for (int m = 0; m < 4; ++m)
            a[m] = *reinterpret_cast<const bf16x8*>(Ap + (size_t)(m * 16) * K + kk);
        #pragma unroll
        for (int n = 0; n < 4; ++n)
            b[n] = *reinterpret_cast<const bf16x8*>(Bp + (size_t)(n * 16) * K + kk);
        #pragma unroll
        for (int m = 0; m < 4; ++m)
            #pragma unroll
            for (int n = 0; n < 4; ++n)
                acc[m][n] = __builtin_amdgcn_mfma_f32_16x16x32_bf16(a[m], b[n], acc[m][n], 0, 0, 0);
    }

    if (MODE == 0) {
        const int part = col0 >> 10;                    // 0=Q 1=K 2=V (uniform per block)
        const float QSC = 0.18033688011112042f;         // DIM_HEAD^-0.5 * log2(e)
        #pragma unroll
        for (int m = 0; m < 4; ++m) {
            const int trow = row0 + m * 16 + 4 * g;
            #pragma unroll
            for (int n = 0; n < 4; ++n) {
                const int c  = col0 + n * 16 + l16;
                const int cc = c & 1023;
                const int h  = cc >> 6, d = cc & 63;
                #pragma unroll
                for (int jj = 0; jj < 4; ++jj) {
                    const int t  = trow + jj;
                    const int bb = t >> 11, nn = t & 2047;
                    const float v = acc[m][n][jj];
                    const size_t bhid = (size_t)(bb * NHEAD + h);
                    if (part == 0)
                        Qb[(bhid * NSEQ + nn) * DHEAD + d] = f32_bf16(v * QSC);
                    else if (part == 1)
                        Kb[(bhid * NSEQ + nn) * DHEAD + d] = f32_bf16(v);
                    else
                        Vtb[(bhid * DHEAD + d) * NSEQ + nn] = f32_bf16(v);
                }
            }
        }
    } else {
        #pragma unroll
        for (int m = 0; m < 4; ++m) {
            const int trow = row0 + m * 16 + 4 * g;
            #pragma unroll
            for (int n = 0; n < 4; ++n) {
                const int c = col0 + n * 16 + l16;
                const float bv = bias[c];
                #pragma unroll
                for (int jj = 0; jj < 4; ++jj)
                    Out[(size_t)(trow + jj) * DMODEL + c] = acc[m][n][jj] + bv;
            }
        }
    }
}

// Causal flash attention, swapped-QK^T form.
// Block: 4 waves, 64 q-rows (16/wave). KV tiles of 64 keys.
// S = mfma(K, Q): lane l16 = q-col, regs = key axis -> in-lane softmax reduce,
// only 2 cross-lane shuffles per reduction. P relayout via per-wave LDS.
__global__ __launch_bounds__(256) void attn_kernel(
    const ushort* __restrict__ Qb, const ushort* __restrict__ Kb,
    const ushort* __restrict__ Vtb, ushort* __restrict__ Ob)
{
    __shared__ __align__(16) ushort p_lds[4][16][72];   // stride 72: 2-way banks (free)
    const int lane = threadIdx.x & 63;
    const int w    = threadIdx.x >> 6;
    const int l16  = lane & 15;
    const int g    = lane >> 4;
    const int bh   = blockIdx.y;                        // b*16 + h
    const int qblk = (int)gridDim.x - 1 - (int)blockIdx.x;  // long blocks dispatch first
    const int qr0  = qblk * 64 + w * 16;

    const ushort* Qp = Qb + ((size_t)bh * NSEQ + qr0 + l16) * DHEAD + 8 * g;
    const bf16x8 qf0 = *reinterpret_cast<const bf16x8*>(Qp);
    const bf16x8 qf1 = *reinterpret_cast<const bf16x8*>(Qp + 32);

    const ushort* Kp = Kb  + ((size_t)bh * NSEQ + l16) * DHEAD + 8 * g;
    const ushort* Vp = Vtb + ((size_t)bh * DHEAD + l16) * NSEQ + 8 * g;

    f32x4 oacc[4] = {};
    float mrun = -1e30f, lsum = 0.f;
    const int qlane = qr0 + l16;
    const int kend  = qr0 + 16;                         // causal: keys <= qr0+15

    for (int kt = 0; kt < kend; kt += 64) {
        // --- QK^T (swapped): s[t] has row=key(4g+jj within 16-tile t), col=q(l16)
        f32x4 zero = {};
        f32x4 s[4];
        #pragma unroll
        for (int t = 0; t < 4; ++t) {
            const ushort* kp = Kp + (size_t)(kt + 16 * t) * DHEAD;
            const bf16x8 k0 = *reinterpret_cast<const bf16x8*>(kp);
            const bf16x8 k1 = *reinterpret_cast<const bf16x8*>(kp + 32);
            s[t] = __builtin_amdgcn_mfma_f32_16x16x32_bf16(k0, qf0, zero, 0, 0, 0);
            s[t] = __builtin_amdgcn_mfma_f32_16x16x32_bf16(k1, qf1, s[t], 0, 0, 0);
        }
        // --- causal mask (only diagonal-straddling tiles)
        if (kt + 63 > qr0) {
            const int kb = kt + 4 * g - qlane;          // key - q = kb + 16t + jj
            #pragma unroll
            for (int t = 0; t < 4; ++t)
                #pragma unroll
                for (int jj = 0; jj < 4; ++jj)
                    if (kb + 16 * t + jj > 0) s[t][jj] = -1e30f;
        }
        // --- row max: 15 in-lane + 2 shuffles
        float mx = fmaxf(fmaxf(s[0][0], s[0][1]), fmaxf(s[0][2], s[0][3]));
        #pragma unroll
        for (int t = 1; t < 4; ++t)
            mx = fmaxf(mx, fmaxf(fmaxf(s[t][0], s[t][1]), fmaxf(s[t][2], s[t][3])));
        mx = fmaxf(mx, __shfl_xor(mx, 16));
        mx = fmaxf(mx, __shfl_xor(mx, 32));
        const float mn = fmaxf(mrun, mx);
        const float sc = __builtin_amdgcn_exp2f(mrun - mn);
        mrun = mn;
        // --- exp + pack + partial sum (in-lane)
        float ps = 0.f;
        uint2 pw[4];
        #pragma unroll
        for (int t = 0; t < 4; ++t) {
            const float p0 = __builtin_amdgcn_exp2f(s[t][0] - mn);
            const float p1 = __builtin_amdgcn_exp2f(s[t][1] - mn);
            const float p2 = __builtin_amdgcn_exp2f(s[t][2] - mn);
            const float p3 = __builtin_amdgcn_exp2f(s[t][3] - mn);
            ps += (p0 + p1) + (p2 + p3);
            pw[t].x = (uint)f32_bf16(p0) | ((uint)f32_bf16(p1) << 16);
            pw[t].y = (uint)f32_bf16(p2) | ((uint)f32_bf16(p3) << 16);
        }
        ps += __shfl_xor(ps, 16);
        ps += __shfl_xor(ps, 32);
        lsum = lsum * sc + ps;
        // --- stage P into LDS: row q=l16, key offset 16t+4g
        #pragma unroll
        for (int t = 0; t < 4; ++t)
            *reinterpret_cast<uint2*>(&p_lds[w][l16][16 * t + 4 * g]) = pw[t];
        // --- rescale O (sc lives at lane l16=q; oacc rows are q=4g+jj)
        float scj[4];
        #pragma unroll
        for (int jj = 0; jj < 4; ++jj) scj[jj] = __shfl(sc, 4 * g + jj);
        #pragma unroll
        for (int dt = 0; dt < 4; ++dt)
            #pragma unroll
            for (int jj = 0; jj < 4; ++jj) oacc[dt][jj] *= scj[jj];
        asm volatile("s_waitcnt lgkmcnt(0)" ::: "memory");
        // --- PV: A = P (row=q=l16, k=key), B = V^T (col=d=l16, k=key)
        const bf16x8 pf0 = *reinterpret_cast<const bf16x8*>(&p_lds[w][l16][8 * g]);
        const bf16x8 pf1 = *reinterpret_cast<const bf16x8*>(&p_lds[w][l16][32 + 8 * g]);
        #pragma unroll
        for (int dt = 0; dt < 4; ++dt) {
            const ushort* vp = Vp + (size_t)(dt * 16) * NSEQ + kt;
            const bf16x8 v0 = *reinterpret_cast<const bf16x8*>(vp);
            const bf16x8 v1 = *reinterpret_cast<const bf16x8*>(vp + 32);
            oacc[dt] = __builtin_amdgcn_mfma_f32_16x16x32_bf16(pf0, v0, oacc[dt], 0, 0, 0);
            oacc[dt] = __builtin_amdgcn_mfma_f32_16x16x32_bf16(pf1, v1, oacc[dt], 0, 0, 0);
        }
    }

    const float inv = 1.0f / lsum;
    float invj[4];
    #pragma unroll
    for (int jj = 0; jj < 4; ++jj) invj[jj] = __shfl(inv, 4 * g + jj);
    const int bb = bh >> 4, h = bh & 15;
    #pragma unroll
    for (int jj = 0; jj < 4; ++jj) {
        const size_t t = (size_t)bb * NSEQ + qr0 + 4 * g + jj;
        #pragma unroll
        for (int dt = 0; dt < 4; ++dt)
            Ob[t * DMODEL + h * DHEAD + dt * 16 + l16] = f32_bf16(oacc[dt][jj] * invj[jj]);
    }
}

extern "C" void kernel_launch(void* const* d_in, const int* in_sizes, int n_in,
                              void* d_out, int out_size, void* d_ws, size_t ws_size,
                              hipStream_t stream)
{
    const float* x     = (const float*)d_in[0];
    const float* w_qkv = (const float*)d_in[1];
    const float* w_out = (const float*)d_in[2];
    const float* b_out = (const float*)d_in[3];
    float* out = (float*)d_out;

    char* ws = (char*)d_ws;
    // workspace layout (bytes); total 75,497,472
    ushort* x_bf   = (ushort*)(ws);                    // 16,777,216  (reused as attn out)
    ushort* wqkv_t = (ushort*)(ws + 16777216);         //  6,291,456
    ushort* wout_t = (ushort*)(ws + 23068672);         //  2,097,152
    ushort* q_bf   = (ushort*)(ws + 25165824);         // 16,777,216
    ushort* k_bf   = (ushort*)(ws + 41943040);         // 16,777,216
    ushort* vt_bf  = (ushort*)(ws + 58720256);         // 16,777,216
    ushort* attn_bf = x_bf;                            // alias: x_bf dead after QKV GEMM

    cvt_x_kernel<<<dim3(TOKENS * DMODEL / 4 / 256), dim3(256), 0, stream>>>(x, x_bf);
    cvt_wt_kernel<<<dim3(NQKV * 1024 / 256), dim3(256), 0, stream>>>(w_qkv, wqkv_t, NQKV);
    cvt_wt_kernel<<<dim3(1024 * 1024 / 256), dim3(256), 0, stream>>>(w_out, wout_t, 1024);

    gemm_bt<0><<<dim3(NQKV / 128, TOKENS / 128), dim3(256), 0, stream>>>(
        x_bf, wqkv_t, q_bf, k_bf, vt_bf, nullptr, nullptr);

    attn_kernel<<<dim3(NSEQ / 64, 64), dim3(256), 0, stream>>>(q_bf, k_bf, vt_bf, attn_bf);

    gemm_bt<1><<<dim3(DMODEL / 128, TOKENS / 128), dim3(256), 0, stream>>>(
        attn_bf, wout_t, nullptr, nullptr, nullptr, out, b_out);
}

// Round 3
// 463.044 us; speedup vs baseline: 1.5973x; 1.5957x over previous
//
#include <hip/hip_runtime.h>
#include <hip/hip_bf16.h>
#include <stdint.h>

typedef __attribute__((ext_vector_type(8))) short bf16x8;
typedef __attribute__((ext_vector_type(4))) float f32x4;
typedef __attribute__((ext_vector_type(4))) unsigned int uint32x4;

#define TOKENS 8192
#define DMODEL 1024
#define NQKV   3072
#define NSEQ   2048
#define NHEAD  16
#define DHEAD  64

__device__ __forceinline__ ushort f32_bf16(float f) {
    uint32_t u = __builtin_bit_cast(uint32_t, f);
    u = (u + 0x7fffu + ((u >> 16) & 1u)) >> 16;
    return (ushort)u;
}

__device__ __forceinline__ unsigned int cvt_pk_bf16(float lo, float hi) {
    unsigned int r;
    asm("v_cvt_pk_bf16_f32 %0, %1, %2" : "=v"(r) : "v"(lo), "v"(hi));
    return r;
}
__device__ __forceinline__ void permlane32_swap(unsigned int& a, unsigned int& b) {
    asm("v_permlane32_swap_b32 %0, %1" : "+v"(a), "+v"(b));
}
__device__ __forceinline__ void permlane16_swap(unsigned int& a, unsigned int& b) {
    asm("v_permlane16_swap_b32 %0, %1" : "+v"(a), "+v"(b));
}

// x [8192][1024] f32 -> bf16 (vectorized by 4)
__global__ void cvt_x_kernel(const float* __restrict__ x, ushort* __restrict__ xb) {
    int i = blockIdx.x * 256 + threadIdx.x;
    float4 v = reinterpret_cast<const float4*>(x)[i];
    ushort4 o;
    o.x = f32_bf16(v.x); o.y = f32_bf16(v.y);
    o.z = f32_bf16(v.z); o.w = f32_bf16(v.w);
    reinterpret_cast<ushort4*>(xb)[i] = o;
}

// w [1024][N] f32 -> wt [N][1024] bf16 (coalesced writes)
__global__ void cvt_wt_kernel(const float* __restrict__ w, ushort* __restrict__ wt, int N) {
    int i = blockIdx.x * 256 + threadIdx.x;   // i = n*1024 + k
    int k = i & 1023;
    int n = i >> 10;
    if (n < N) wt[i] = f32_bf16(w[(size_t)k * N + n]);
}

// C = A[M][1024] @ Bt[N][1024]^T, 128x128 block tile, 4 waves x 64x64.
// MODE 0: scatter to Q (scaled), K, V^T(tiled) bf16 buffers. MODE 1: f32 out + bias.
template<int MODE>
__global__ __launch_bounds__(256) void gemm_bt(
    const ushort* __restrict__ A, const ushort* __restrict__ Bt,
    ushort* __restrict__ Qb, ushort* __restrict__ Kb, ushort* __restrict__ Vtb,
    float* __restrict__ Out, const float* __restrict__ bias)
{
    constexpr int K = 1024;
    const int lane = threadIdx.x & 63;
    const int w    = threadIdx.x >> 6;
    const int l16  = lane & 15;
    const int g    = lane >> 4;
    const int row0 = blockIdx.y * 128 + (w >> 1) * 64;
    const int col0 = blockIdx.x * 128 + (w & 1) * 64;

    f32x4 acc[4][4] = {};
    const ushort* Ap = A  + (size_t)(row0 + l16) * K + 8 * g;
    const ushort* Bp = Bt + (size_t)(col0 + l16) * K + 8 * g;

    for (int kk = 0; kk < K; kk += 32) {
        bf16x8 a[4], b[4];
        #pragma unroll
        for (int m = 0; m < 4; ++m)
            a[m] = *reinterpret_cast<const bf16x8*>(Ap + (size_t)(m * 16) * K + kk);
        #pragma unroll
        for (int n = 0; n < 4; ++n)
            b[n] = *reinterpret_cast<const bf16x8*>(Bp + (size_t)(n * 16) * K + kk);
        #pragma unroll
        for (int m = 0; m < 4; ++m)
            #pragma unroll
            for (int n = 0; n < 4; ++n)
                acc[m][n] = __builtin_amdgcn_mfma_f32_16x16x32_bf16(a[m], b[n], acc[m][n], 0, 0, 0);
    }

    if (MODE == 0) {
        const int part = col0 >> 10;                    // 0=Q 1=K 2=V (uniform per block)
        const float QSC = 0.18033688011112042f;         // DIM_HEAD^-0.5 * log2(e)
        #pragma unroll
        for (int m = 0; m < 4; ++m) {
            const int trow = row0 + m * 16 + 4 * g;
            #pragma unroll
            for (int n = 0; n < 4; ++n) {
                const int c  = col0 + n * 16 + l16;
                const int cc = c & 1023;
                const int h  = cc >> 6, d = cc & 63;
                #pragma unroll
                for (int jj = 0; jj < 4; ++jj) {
                    const int t  = trow + jj;
                    const int bb = t >> 11, nn = t & 2047;
                    const float v = acc[m][n][jj];
                    const size_t bhid = (size_t)(bb * NHEAD + h);
                    if (part == 0)
                        Qb[(bhid * NSEQ + nn) * DHEAD + d] = f32_bf16(v * QSC);
                    else if (part == 1)
                        Kb[(bhid * NSEQ + nn) * DHEAD + d] = f32_bf16(v);
                    else  // V^T tiled: [bh][n/32][d:64][n%32]
                        Vtb[bhid * (NSEQ * DHEAD) + (size_t)(nn >> 5) * (DHEAD * 32)
                            + d * 32 + (nn & 31)] = f32_bf16(v);
                }
            }
        }
    } else {
        #pragma unroll
        for (int m = 0; m < 4; ++m) {
            const int trow = row0 + m * 16 + 4 * g;
            #pragma unroll
            for (int n = 0; n < 4; ++n) {
                const int c = col0 + n * 16 + l16;
                const float bv = bias[c];
                #pragma unroll
                for (int jj = 0; jj < 4; ++jj)
                    Out[(size_t)(trow + jj) * DMODEL + c] = acc[m][n][jj] + bv;
            }
        }
    }
}

// One 64-key tile of causal flash attention for one 16-row q-tile, fully
// in-register. Swapped QK^T: lane(l16,g) holds S[key=16t+4g+jj][q=l16].
// P relayout to PV A-fragment via cvt_pk + permlane32/16_swap (T12).
__device__ __forceinline__ void attn_tile(
    int kt, int qr0s, int l16, int g,
    const bf16x8 (&kk)[4][2], const bf16x8 (&vv)[4][2],
    const bf16x8 qf0, const bf16x8 qf1,
    f32x4 (&oacc)[4], float& mrun, float& lsum)
{
    const f32x4 zero = {};
    f32x4 s[4];
    #pragma unroll
    for (int t = 0; t < 4; ++t) {
        s[t] = __builtin_amdgcn_mfma_f32_16x16x32_bf16(kk[t][0], qf0, zero, 0, 0, 0);
        s[t] = __builtin_amdgcn_mfma_f32_16x16x32_bf16(kk[t][1], qf1, s[t], 0, 0, 0);
    }
    if (kt + 63 > qr0s) {                               // diagonal tiles only
        const int kb = kt + 4 * g - (qr0s + l16);       // key - q = kb + 16t + jj
        #pragma unroll
        for (int t = 0; t < 4; ++t)
            #pragma unroll
            for (int jj = 0; jj < 4; ++jj)
                if (kb + 16 * t + jj > 0) s[t][jj] = -1e30f;
    }
    // row max: 15 in-lane + 2 shuffles (replicated across g afterwards)
    float mx = fmaxf(fmaxf(s[0][0], s[0][1]), fmaxf(s[0][2], s[0][3]));
    #pragma unroll
    for (int t = 1; t < 4; ++t)
        mx = fmaxf(mx, fmaxf(fmaxf(s[t][0], s[t][1]), fmaxf(s[t][2], s[t][3])));
    mx = fmaxf(mx, __shfl_xor(mx, 16));
    mx = fmaxf(mx, __shfl_xor(mx, 32));
    const float mn = fmaxf(mrun, mx);
    const float sc = __builtin_amdgcn_exp2f(mrun - mn);
    mrun = mn;
    // exp + pack (in-lane)
    float ps = 0.f;
    unsigned int pw[4][2];
    #pragma unroll
    for (int t = 0; t < 4; ++t) {
        const float p0 = __builtin_amdgcn_exp2f(s[t][0] - mn);
        const float p1 = __builtin_amdgcn_exp2f(s[t][1] - mn);
        const float p2 = __builtin_amdgcn_exp2f(s[t][2] - mn);
        const float p3 = __builtin_amdgcn_exp2f(s[t][3] - mn);
        ps += (p0 + p1) + (p2 + p3);
        pw[t][0] = cvt_pk_bf16(p0, p1);
        pw[t][1] = cvt_pk_bf16(p2, p3);
    }
    ps += __shfl_xor(ps, 16);
    ps += __shfl_xor(ps, 32);
    lsum = lsum * sc + ps;
    // relayout: target lane(l16,g) word i <- (tile g>>1 pair, src group 2(g&1)+(i>>1))
    unsigned int a0 = pw[0][0], a1 = pw[0][1], b0 = pw[1][0], b1 = pw[1][1];
    permlane32_swap(a0, b0); permlane32_swap(a1, b1);
    permlane16_swap(a0, b0); permlane16_swap(a1, b1);
    const bf16x8 pf0 = __builtin_bit_cast(bf16x8, (uint32x4){a0, a1, b0, b1});
    unsigned int c0 = pw[2][0], c1 = pw[2][1], d0 = pw[3][0], d1 = pw[3][1];
    permlane32_swap(c0, d0); permlane32_swap(c1, d1);
    permlane16_swap(c0, d0); permlane16_swap(c1, d1);
    const bf16x8 pf1 = __builtin_bit_cast(bf16x8, (uint32x4){c0, c1, d0, d1});
    // rescale O (sc at lane l16=q; oacc rows are q=4g+jj)
    float scj[4];
    #pragma unroll
    for (int jj = 0; jj < 4; ++jj) scj[jj] = __shfl(sc, 4 * g + jj);
    #pragma unroll
    for (int dt = 0; dt < 4; ++dt)
        #pragma unroll
        for (int jj = 0; jj < 4; ++jj) oacc[dt][jj] *= scj[jj];
    // PV
    #pragma unroll
    for (int dt = 0; dt < 4; ++dt) {
        oacc[dt] = __builtin_amdgcn_mfma_f32_16x16x32_bf16(pf0, vv[dt][0], oacc[dt], 0, 0, 0);
        oacc[dt] = __builtin_amdgcn_mfma_f32_16x16x32_bf16(pf1, vv[dt][1], oacc[dt], 0, 0, 0);
    }
}

// Causal flash attention. Block: 4 waves; each wave owns TWO 16-row q-tiles
// from complementary blocks {j, 31-j} -> equal work per block (33 tile-iters),
// K/V tile loads shared between the two q-tiles. No LDS, no barriers.
__global__ __launch_bounds__(256) void attn_kernel(
    const ushort* __restrict__ Qb, const ushort* __restrict__ Kb,
    const ushort* __restrict__ Vt, ushort* __restrict__ Ob)
{
    const int lane = threadIdx.x & 63;
    const int w    = threadIdx.x >> 6;
    const int l16  = lane & 15;
    const int g    = lane >> 4;
    const int bh   = blockIdx.y;                        // b*16 + h
    const int jlo  = blockIdx.x;                        // 0..15
    const int jhi  = 31 - jlo;

    const int qr0_lo = jlo * 64 + w * 16;
    const int qr0_hi = jhi * 64 + w * 16;
    const int kend_lo = qr0_lo + 16;
    const int kend_hi = qr0_hi + 16;

    const ushort* QpL = Qb + ((size_t)bh * NSEQ + qr0_lo + l16) * DHEAD + 8 * g;
    const ushort* QpH = Qb + ((size_t)bh * NSEQ + qr0_hi + l16) * DHEAD + 8 * g;
    const bf16x8 qfL0 = *reinterpret_cast<const bf16x8*>(QpL);
    const bf16x8 qfL1 = *reinterpret_cast<const bf16x8*>(QpL + 32);
    const bf16x8 qfH0 = *reinterpret_cast<const bf16x8*>(QpH);
    const bf16x8 qfH1 = *reinterpret_cast<const bf16x8*>(QpH + 32);

    const ushort* Kp = Kb + ((size_t)bh * NSEQ + l16) * DHEAD + 8 * g;
    const ushort* Vp = Vt + (size_t)bh * (NSEQ * DHEAD) + (size_t)l16 * 32 + 8 * g;

    f32x4 oaccL[4] = {}, oaccH[4] = {};
    float mrunL = -1e30f, lsumL = 0.f, mrunH = -1e30f, lsumH = 0.f;

    for (int kt = 0; kt < kend_hi; kt += 64) {
        bf16x8 kk[4][2];
        #pragma unroll
        for (int t = 0; t < 4; ++t) {
            const ushort* kp = Kp + (size_t)(kt + 16 * t) * DHEAD;
            kk[t][0] = *reinterpret_cast<const bf16x8*>(kp);
            kk[t][1] = *reinterpret_cast<const bf16x8*>(kp + 32);
        }
        bf16x8 vv[4][2];
        #pragma unroll
        for (int dt = 0; dt < 4; ++dt) {
            const ushort* vp = Vp + (size_t)(kt >> 5) * (DHEAD * 32) + dt * (16 * 32);
            vv[dt][0] = *reinterpret_cast<const bf16x8*>(vp);
            vv[dt][1] = *reinterpret_cast<const bf16x8*>(vp + DHEAD * 32);
        }
        attn_tile(kt, qr0_hi, l16, g, kk, vv, qfH0, qfH1, oaccH, mrunH, lsumH);
        if (kt < kend_lo)
            attn_tile(kt, qr0_lo, l16, g, kk, vv, qfL0, qfL1, oaccL, mrunL, lsumL);
    }

    const int bb = bh >> 4, h = bh & 15;
    {
        const float inv = 1.0f / lsumH;
        float invj[4];
        #pragma unroll
        for (int jj = 0; jj < 4; ++jj) invj[jj] = __shfl(inv, 4 * g + jj);
        #pragma unroll
        for (int jj = 0; jj < 4; ++jj) {
            const size_t t = (size_t)bb * NSEQ + qr0_hi + 4 * g + jj;
            #pragma unroll
            for (int dt = 0; dt < 4; ++dt)
                Ob[t * DMODEL + h * DHEAD + dt * 16 + l16] = f32_bf16(oaccH[dt][jj] * invj[jj]);
        }
    }
    {
        const float inv = 1.0f / lsumL;
        float invj[4];
        #pragma unroll
        for (int jj = 0; jj < 4; ++jj) invj[jj] = __shfl(inv, 4 * g + jj);
        #pragma unroll
        for (int jj = 0; jj < 4; ++jj) {
            const size_t t = (size_t)bb * NSEQ + qr0_lo + 4 * g + jj;
            #pragma unroll
            for (int dt = 0; dt < 4; ++dt)
                Ob[t * DMODEL + h * DHEAD + dt * 16 + l16] = f32_bf16(oaccL[dt][jj] * invj[jj]);
        }
    }
}

extern "C" void kernel_launch(void* const* d_in, const int* in_sizes, int n_in,
                              void* d_out, int out_size, void* d_ws, size_t ws_size,
                              hipStream_t stream)
{
    const float* x     = (const float*)d_in[0];
    const float* w_qkv = (const float*)d_in[1];
    const float* w_out = (const float*)d_in[2];
    const float* b_out = (const float*)d_in[3];
    float* out = (float*)d_out;

    char* ws = (char*)d_ws;
    // workspace layout (bytes); total 75,497,472
    ushort* x_bf   = (ushort*)(ws);                    // 16,777,216  (reused as attn out)
    ushort* wqkv_t = (ushort*)(ws + 16777216);         //  6,291,456
    ushort* wout_t = (ushort*)(ws + 23068672);         //  2,097,152
    ushort* q_bf   = (ushort*)(ws + 25165824);         // 16,777,216
    ushort* k_bf   = (ushort*)(ws + 41943040);         // 16,777,216
    ushort* vt_bf  = (ushort*)(ws + 58720256);         // 16,777,216 (V^T tiled)
    ushort* attn_bf = x_bf;                            // alias: x_bf dead after QKV GEMM

    cvt_x_kernel<<<dim3(TOKENS * DMODEL / 4 / 256), dim3(256), 0, stream>>>(x, x_bf);
    cvt_wt_kernel<<<dim3(NQKV * 1024 / 256), dim3(256), 0, stream>>>(w_qkv, wqkv_t, NQKV);
    cvt_wt_kernel<<<dim3(1024 * 1024 / 256), dim3(256), 0, stream>>>(w_out, wout_t, 1024);

    gemm_bt<0><<<dim3(NQKV / 128, TOKENS / 128), dim3(256), 0, stream>>>(
        x_bf, wqkv_t, q_bf, k_bf, vt_bf, nullptr, nullptr);

    attn_kernel<<<dim3(16, 64), dim3(256), 0, stream>>>(q_bf, k_bf, vt_bf, attn_bf);

    gemm_bt<1><<<dim3(DMODEL / 128, TOKENS / 128), dim3(256), 0, stream>>>(
        attn_bf, wout_t, nullptr, nullptr, nullptr, out, b_out);
}

// Round 4
// 303.843 us; speedup vs baseline: 2.4342x; 1.5240x over previous
//
#include <hip/hip_runtime.h>
#include <hip/hip_bf16.h>
#include <stdint.h>

typedef __attribute__((ext_vector_type(8))) short bf16x8;
typedef __attribute__((ext_vector_type(4))) float f32x4;
typedef __attribute__((ext_vector_type(4))) unsigned int uint32x4;

#define TOKENS 8192
#define DMODEL 1024
#define NQKV   3072
#define NSEQ   2048
#define NHEAD  16
#define DHEAD  64

__device__ __forceinline__ ushort f32_bf16(float f) {
    uint32_t u = __builtin_bit_cast(uint32_t, f);
    u = (u + 0x7fffu + ((u >> 16) & 1u)) >> 16;
    return (ushort)u;
}

__device__ __forceinline__ unsigned int cvt_pk_bf16(float lo, float hi) {
    unsigned int r;
    asm("v_cvt_pk_bf16_f32 %0, %1, %2" : "=v"(r) : "v"(lo), "v"(hi));
    return r;
}
__device__ __forceinline__ void permlane32_swap(unsigned int& a, unsigned int& b) {
    asm("v_permlane32_swap_b32 %0, %1" : "+v"(a), "+v"(b));
}
__device__ __forceinline__ void permlane16_swap(unsigned int& a, unsigned int& b) {
    asm("v_permlane16_swap_b32 %0, %1" : "+v"(a), "+v"(b));
}

// async global->LDS, 16B per lane; LDS dest = wave-uniform base + lane*16
__device__ __forceinline__ void gload16(const void* g, void* l) {
    __builtin_amdgcn_global_load_lds(
        (const __attribute__((address_space(1))) void*)g,
        (__attribute__((address_space(3))) void*)l, 16, 0, 0);
}

// x [8192][1024] f32 -> bf16 (vectorized by 4)
__global__ void cvt_x_kernel(const float* __restrict__ x, ushort* __restrict__ xb) {
    int i = blockIdx.x * 256 + threadIdx.x;
    float4 v = reinterpret_cast<const float4*>(x)[i];
    ushort4 o;
    o.x = f32_bf16(v.x); o.y = f32_bf16(v.y);
    o.z = f32_bf16(v.z); o.w = f32_bf16(v.w);
    reinterpret_cast<ushort4*>(xb)[i] = o;
}

// w [1024][N] f32 -> wt [N][1024] bf16 via 64x64 LDS tile (both sides coalesced)
__global__ __launch_bounds__(256) void cvt_wt_kernel(
    const float* __restrict__ w, ushort* __restrict__ wt, int N)
{
    __shared__ float tile[64][65];
    const int tid = threadIdx.x;
    const int r  = tid >> 4;          // 0..15
    const int c4 = (tid & 15) * 4;    // 0,4,..,60
    const int n0 = blockIdx.x * 64;
    const int k0 = blockIdx.y * 64;
    #pragma unroll
    for (int i = 0; i < 4; ++i) {
        const float4 v = *reinterpret_cast<const float4*>(&w[(size_t)(k0 + r + i * 16) * N + n0 + c4]);
        tile[r + i * 16][c4 + 0] = v.x;
        tile[r + i * 16][c4 + 1] = v.y;
        tile[r + i * 16][c4 + 2] = v.z;
        tile[r + i * 16][c4 + 3] = v.w;
    }
    __syncthreads();
    #pragma unroll
    for (int i = 0; i < 4; ++i) {
        ushort4 o;
        o.x = f32_bf16(tile[c4 + 0][r + i * 16]);
        o.y = f32_bf16(tile[c4 + 1][r + i * 16]);
        o.z = f32_bf16(tile[c4 + 2][r + i * 16]);
        o.w = f32_bf16(tile[c4 + 3][r + i * 16]);
        *reinterpret_cast<ushort4*>(&wt[(size_t)(n0 + r + i * 16) * 1024 + k0 + c4]) = o;
    }
}

// C = A[M][1024] @ Bt[N][1024]^T. m97 structure: 128x128 tile, BK=32,
// global_load_lds width=16 staging, 2 barriers/K-step, 4 waves x 64x64.
// MODE 0: scatter to Q (scaled), K, V^T(tiled) bf16. MODE 1: f32 out + bias.
template<int MODE>
__global__ __launch_bounds__(256) void gemm_bt(
    const ushort* __restrict__ A, const ushort* __restrict__ Bt,
    ushort* __restrict__ Qb, ushort* __restrict__ Kb, ushort* __restrict__ Vtb,
    float* __restrict__ Out, const float* __restrict__ bias)
{
    constexpr int K = 1024;
    __shared__ __align__(16) ushort As[128 * 32];
    __shared__ __align__(16) ushort Bs[128 * 32];

    const int lane = threadIdx.x & 63;
    const int w    = threadIdx.x >> 6;
    const int l16  = lane & 15;
    const int g    = lane >> 4;
    const int row0 = blockIdx.y * 128;
    const int col0 = blockIdx.x * 128;
    const int wr   = (w >> 1) * 64;
    const int wc   = (w & 1) * 64;

    // staging map: lane l of wave w -> tile row w*16 + l/4, k-col (l%4)*8
    const int srow = w * 16 + (lane >> 2);
    const int scol = (lane & 3) * 8;
    const ushort* Ag = A  + (size_t)(row0 + srow) * K + scol;
    const ushort* Bg = Bt + (size_t)(col0 + srow) * K + scol;
    ushort* AsW = As + w * (16 * 32);
    ushort* BsW = Bs + w * (16 * 32);

    f32x4 acc[4][4] = {};

    for (int kk = 0; kk < K; kk += 32) {
        gload16(Ag + kk,          AsW);
        gload16(Ag + 64 * K + kk, AsW + 64 * 32);
        gload16(Bg + kk,          BsW);
        gload16(Bg + 64 * K + kk, BsW + 64 * 32);
        __syncthreads();                       // drains vmcnt(0) then s_barrier
        bf16x8 a[4], b[4];
        #pragma unroll
        for (int m = 0; m < 4; ++m)
            a[m] = *reinterpret_cast<const bf16x8*>(&As[(wr + m * 16 + l16) * 32 + 8 * g]);
        #pragma unroll
        for (int n = 0; n < 4; ++n)
            b[n] = *reinterpret_cast<const bf16x8*>(&Bs[(wc + n * 16 + l16) * 32 + 8 * g]);
        #pragma unroll
        for (int m = 0; m < 4; ++m)
            #pragma unroll
            for (int n = 0; n < 4; ++n)
                acc[m][n] = __builtin_amdgcn_mfma_f32_16x16x32_bf16(a[m], b[n], acc[m][n], 0, 0, 0);
        __syncthreads();                       // before next stage overwrites LDS
    }

    if (MODE == 0) {
        const int part = col0 >> 10;                    // 0=Q 1=K 2=V (uniform per block)
        const float QSC = 0.18033688011112042f;         // DIM_HEAD^-0.5 * log2(e)
        #pragma unroll
        for (int m = 0; m < 4; ++m) {
            const int trow = row0 + wr + m * 16 + 4 * g;
            #pragma unroll
            for (int n = 0; n < 4; ++n) {
                const int c  = col0 + wc + n * 16 + l16;
                const int cc = c & 1023;
                const int h  = cc >> 6, d = cc & 63;
                #pragma unroll
                for (int jj = 0; jj < 4; ++jj) {
                    const int t  = trow + jj;
                    const int bb = t >> 11, nn = t & 2047;
                    const float v = acc[m][n][jj];
                    const size_t bhid = (size_t)(bb * NHEAD + h);
                    if (part == 0)
                        Qb[(bhid * NSEQ + nn) * DHEAD + d] = f32_bf16(v * QSC);
                    else if (part == 1)
                        Kb[(bhid * NSEQ + nn) * DHEAD + d] = f32_bf16(v);
                    else  // V^T tiled: [bh][n/32][d:64][n%32]
                        Vtb[bhid * (NSEQ * DHEAD) + (size_t)(nn >> 5) * (DHEAD * 32)
                            + d * 32 + (nn & 31)] = f32_bf16(v);
                }
            }
        }
    } else {
        #pragma unroll
        for (int m = 0; m < 4; ++m) {
            const int trow = row0 + wr + m * 16 + 4 * g;
            #pragma unroll
            for (int n = 0; n < 4; ++n) {
                const int c = col0 + wc + n * 16 + l16;
                const float bv = bias[c];
                #pragma unroll
                for (int jj = 0; jj < 4; ++jj)
                    Out[(size_t)(trow + jj) * DMODEL + c] = acc[m][n][jj] + bv;
            }
        }
    }
}

// One 64-key tile of causal flash attention for one 16-row q-tile, fully
// in-register. Swapped QK^T: lane(l16,g) holds S[key=16t+4g+jj][q=l16].
// P relayout to PV A-fragment via cvt_pk + permlane32/16_swap (T12).
__device__ __forceinline__ void attn_tile(
    int kt, int qr0s, int l16, int g,
    const bf16x8 (&kk)[4][2], const bf16x8 (&vv)[4][2],
    const bf16x8 qf0, const bf16x8 qf1,
    f32x4 (&oacc)[4], float& mrun, float& lsum)
{
    const f32x4 zero = {};
    f32x4 s[4];
    #pragma unroll
    for (int t = 0; t < 4; ++t) {
        s[t] = __builtin_amdgcn_mfma_f32_16x16x32_bf16(kk[t][0], qf0, zero, 0, 0, 0);
        s[t] = __builtin_amdgcn_mfma_f32_16x16x32_bf16(kk[t][1], qf1, s[t], 0, 0, 0);
    }
    if (kt + 63 > qr0s) {                               // diagonal tiles only
        const int kb = kt + 4 * g - (qr0s + l16);       // key - q = kb + 16t + jj
        #pragma unroll
        for (int t = 0; t < 4; ++t)
            #pragma unroll
            for (int jj = 0; jj < 4; ++jj)
                if (kb + 16 * t + jj > 0) s[t][jj] = -1e30f;
    }
    // row max: 15 in-lane + 2 shuffles (replicated across g afterwards)
    float mx = fmaxf(fmaxf(s[0][0], s[0][1]), fmaxf(s[0][2], s[0][3]));
    #pragma unroll
    for (int t = 1; t < 4; ++t)
        mx = fmaxf(mx, fmaxf(fmaxf(s[t][0], s[t][1]), fmaxf(s[t][2], s[t][3])));
    mx = fmaxf(mx, __shfl_xor(mx, 16));
    mx = fmaxf(mx, __shfl_xor(mx, 32));
    const float mn = fmaxf(mrun, mx);
    const float sc = __builtin_amdgcn_exp2f(mrun - mn);
    mrun = mn;
    // exp + pack (in-lane)
    float ps = 0.f;
    unsigned int pw[4][2];
    #pragma unroll
    for (int t = 0; t < 4; ++t) {
        const float p0 = __builtin_amdgcn_exp2f(s[t][0] - mn);
        const float p1 = __builtin_amdgcn_exp2f(s[t][1] - mn);
        const float p2 = __builtin_amdgcn_exp2f(s[t][2] - mn);
        const float p3 = __builtin_amdgcn_exp2f(s[t][3] - mn);
        ps += (p0 + p1) + (p2 + p3);
        pw[t][0] = cvt_pk_bf16(p0, p1);
        pw[t][1] = cvt_pk_bf16(p2, p3);
    }
    ps += __shfl_xor(ps, 16);
    ps += __shfl_xor(ps, 32);
    lsum = lsum * sc + ps;
    // relayout: target lane(l16,g) word i <- (tile g>>1 pair, src group 2(g&1)+(i>>1))
    unsigned int a0 = pw[0][0], a1 = pw[0][1], b0 = pw[1][0], b1 = pw[1][1];
    permlane32_swap(a0, b0); permlane32_swap(a1, b1);
    permlane16_swap(a0, b0); permlane16_swap(a1, b1);
    const bf16x8 pf0 = __builtin_bit_cast(bf16x8, (uint32x4){a0, a1, b0, b1});
    unsigned int c0 = pw[2][0], c1 = pw[2][1], d0 = pw[3][0], d1 = pw[3][1];
    permlane32_swap(c0, d0); permlane32_swap(c1, d1);
    permlane16_swap(c0, d0); permlane16_swap(c1, d1);
    const bf16x8 pf1 = __builtin_bit_cast(bf16x8, (uint32x4){c0, c1, d0, d1});
    // rescale O (sc at lane l16=q; oacc rows are q=4g+jj)
    float scj[4];
    #pragma unroll
    for (int jj = 0; jj < 4; ++jj) scj[jj] = __shfl(sc, 4 * g + jj);
    #pragma unroll
    for (int dt = 0; dt < 4; ++dt)
        #pragma unroll
        for (int jj = 0; jj < 4; ++jj) oacc[dt][jj] *= scj[jj];
    // PV
    #pragma unroll
    for (int dt = 0; dt < 4; ++dt) {
        oacc[dt] = __builtin_amdgcn_mfma_f32_16x16x32_bf16(pf0, vv[dt][0], oacc[dt], 0, 0, 0);
        oacc[dt] = __builtin_amdgcn_mfma_f32_16x16x32_bf16(pf1, vv[dt][1], oacc[dt], 0, 0, 0);
    }
}

// Causal flash attention. Block: 4 waves; each wave owns TWO 16-row q-tiles
// from complementary blocks {j, 31-j} -> equal work per block (33 tile-iters),
// K/V tile loads shared between the two q-tiles. No LDS, no barriers.
__global__ __launch_bounds__(256) void attn_kernel(
    const ushort* __restrict__ Qb, const ushort* __restrict__ Kb,
    const ushort* __restrict__ Vt, ushort* __restrict__ Ob)
{
    const int lane = threadIdx.x & 63;
    const int w    = threadIdx.x >> 6;
    const int l16  = lane & 15;
    const int g    = lane >> 4;
    const int bh   = blockIdx.y;                        // b*16 + h
    const int jlo  = blockIdx.x;                        // 0..15
    const int jhi  = 31 - jlo;

    const int qr0_lo = jlo * 64 + w * 16;
    const int qr0_hi = jhi * 64 + w * 16;
    const int kend_lo = qr0_lo + 16;
    const int kend_hi = qr0_hi + 16;

    const ushort* QpL = Qb + ((size_t)bh * NSEQ + qr0_lo + l16) * DHEAD + 8 * g;
    const ushort* QpH = Qb + ((size_t)bh * NSEQ + qr0_hi + l16) * DHEAD + 8 * g;
    const bf16x8 qfL0 = *reinterpret_cast<const bf16x8*>(QpL);
    const bf16x8 qfL1 = *reinterpret_cast<const bf16x8*>(QpL + 32);
    const bf16x8 qfH0 = *reinterpret_cast<const bf16x8*>(QpH);
    const bf16x8 qfH1 = *reinterpret_cast<const bf16x8*>(QpH + 32);

    const ushort* Kp = Kb + ((size_t)bh * NSEQ + l16) * DHEAD + 8 * g;
    const ushort* Vp = Vt + (size_t)bh * (NSEQ * DHEAD) + (size_t)l16 * 32 + 8 * g;

    f32x4 oaccL[4] = {}, oaccH[4] = {};
    float mrunL = -1e30f, lsumL = 0.f, mrunH = -1e30f, lsumH = 0.f;

    for (int kt = 0; kt < kend_hi; kt += 64) {
        bf16x8 kk[4][2];
        #pragma unroll
        for (int t = 0; t < 4; ++t) {
            const ushort* kp = Kp + (size_t)(kt + 16 * t) * DHEAD;
            kk[t][0] = *reinterpret_cast<const bf16x8*>(kp);
            kk[t][1] = *reinterpret_cast<const bf16x8*>(kp + 32);
        }
        bf16x8 vv[4][2];
        #pragma unroll
        for (int dt = 0; dt < 4; ++dt) {
            const ushort* vp = Vp + (size_t)(kt >> 5) * (DHEAD * 32) + dt * (16 * 32);
            vv[dt][0] = *reinterpret_cast<const bf16x8*>(vp);
            vv[dt][1] = *reinterpret_cast<const bf16x8*>(vp + DHEAD * 32);
        }
        attn_tile(kt, qr0_hi, l16, g, kk, vv, qfH0, qfH1, oaccH, mrunH, lsumH);
        if (kt < kend_lo)
            attn_tile(kt, qr0_lo, l16, g, kk, vv, qfL0, qfL1, oaccL, mrunL, lsumL);
    }

    const int bb = bh >> 4, h = bh & 15;
    {
        const float inv = 1.0f / lsumH;
        float invj[4];
        #pragma unroll
        for (int jj = 0; jj < 4; ++jj) invj[jj] = __shfl(inv, 4 * g + jj);
        #pragma unroll
        for (int jj = 0; jj < 4; ++jj) {
            const size_t t = (size_t)bb * NSEQ + qr0_hi + 4 * g + jj;
            #pragma unroll
            for (int dt = 0; dt < 4; ++dt)
                Ob[t * DMODEL + h * DHEAD + dt * 16 + l16] = f32_bf16(oaccH[dt][jj] * invj[jj]);
        }
    }
    {
        const float inv = 1.0f / lsumL;
        float invj[4];
        #pragma unroll
        for (int jj = 0; jj < 4; ++jj) invj[jj] = __shfl(inv, 4 * g + jj);
        #pragma unroll
        for (int jj = 0; jj < 4; ++jj) {
            const size_t t = (size_t)bb * NSEQ + qr0_lo + 4 * g + jj;
            #pragma unroll
            for (int dt = 0; dt < 4; ++dt)
                Ob[t * DMODEL + h * DHEAD + dt * 16 + l16] = f32_bf16(oaccL[dt][jj] * invj[jj]);
        }
    }
}

extern "C" void kernel_launch(void* const* d_in, const int* in_sizes, int n_in,
                              void* d_out, int out_size, void* d_ws, size_t ws_size,
                              hipStream_t stream)
{
    const float* x     = (const float*)d_in[0];
    const float* w_qkv = (const float*)d_in[1];
    const float* w_out = (const float*)d_in[2];
    const float* b_out = (const float*)d_in[3];
    float* out = (float*)d_out;

    char* ws = (char*)d_ws;
    // workspace layout (bytes); total 75,497,472
    ushort* x_bf   = (ushort*)(ws);                    // 16,777,216  (reused as attn out)
    ushort* wqkv_t = (ushort*)(ws + 16777216);         //  6,291,456
    ushort* wout_t = (ushort*)(ws + 23068672);         //  2,097,152
    ushort* q_bf   = (ushort*)(ws + 25165824);         // 16,777,216
    ushort* k_bf   = (ushort*)(ws + 41943040);         // 16,777,216
    ushort* vt_bf  = (ushort*)(ws + 58720256);         // 16,777,216 (V^T tiled)
    ushort* attn_bf = x_bf;                            // alias: x_bf dead after QKV GEMM

    cvt_x_kernel<<<dim3(TOKENS * DMODEL / 4 / 256), dim3(256), 0, stream>>>(x, x_bf);
    cvt_wt_kernel<<<dim3(NQKV / 64, 1024 / 64), dim3(256), 0, stream>>>(w_qkv, wqkv_t, NQKV);
    cvt_wt_kernel<<<dim3(1024 / 64, 1024 / 64), dim3(256), 0, stream>>>(w_out, wout_t, 1024);

    gemm_bt<0><<<dim3(NQKV / 128, TOKENS / 128), dim3(256), 0, stream>>>(
        x_bf, wqkv_t, q_bf, k_bf, vt_bf, nullptr, nullptr);

    attn_kernel<<<dim3(16, 64), dim3(256), 0, stream>>>(q_bf, k_bf, vt_bf, attn_bf);

    gemm_bt<1><<<dim3(DMODEL / 128, TOKENS / 128), dim3(256), 0, stream>>>(
        attn_bf, wout_t, nullptr, nullptr, nullptr, out, b_out);
}

// Round 5
// 224.669 us; speedup vs baseline: 3.2920x; 1.3524x over previous
//
#include <hip/hip_runtime.h>
#include <hip/hip_bf16.h>
#include <stdint.h>

typedef __attribute__((ext_vector_type(8))) short bf16x8;
typedef __attribute__((ext_vector_type(4))) float f32x4;
typedef __attribute__((ext_vector_type(4))) unsigned int uint32x4;

#define TOKENS 8192
#define DMODEL 1024
#define NQKV   3072
#define NSEQ   2048
#define NHEAD  16
#define DHEAD  64

__device__ __forceinline__ ushort f32_bf16(float f) {
    uint32_t u = __builtin_bit_cast(uint32_t, f);
    u = (u + 0x7fffu + ((u >> 16) & 1u)) >> 16;
    return (ushort)u;
}

__device__ __forceinline__ unsigned int cvt_pk_bf16(float lo, float hi) {
    unsigned int r;
    asm("v_cvt_pk_bf16_f32 %0, %1, %2" : "=v"(r) : "v"(lo), "v"(hi));
    return r;
}
__device__ __forceinline__ void permlane32_swap(unsigned int& a, unsigned int& b) {
    asm("v_permlane32_swap_b32 %0, %1" : "+v"(a), "+v"(b));
}
__device__ __forceinline__ void permlane16_swap(unsigned int& a, unsigned int& b) {
    asm("v_permlane16_swap_b32 %0, %1" : "+v"(a), "+v"(b));
}

// async global->LDS, 16B per lane; LDS dest = wave-uniform base + lane*16
__device__ __forceinline__ void gload16(const void* g, void* l) {
    __builtin_amdgcn_global_load_lds(
        (const __attribute__((address_space(1))) void*)g,
        (__attribute__((address_space(3))) void*)l, 16, 0, 0);
}

// x [8192][1024] f32 -> bf16 (vectorized by 4)
__global__ void cvt_x_kernel(const float* __restrict__ x, ushort* __restrict__ xb) {
    int i = blockIdx.x * 256 + threadIdx.x;
    float4 v = reinterpret_cast<const float4*>(x)[i];
    ushort4 o;
    o.x = f32_bf16(v.x); o.y = f32_bf16(v.y);
    o.z = f32_bf16(v.z); o.w = f32_bf16(v.w);
    reinterpret_cast<ushort4*>(xb)[i] = o;
}

// w [1024][N] f32 -> wt [N][1024] bf16 via 64x64 LDS tile (both sides coalesced)
__global__ __launch_bounds__(256) void cvt_wt_kernel(
    const float* __restrict__ w, ushort* __restrict__ wt, int N)
{
    __shared__ float tile[64][65];
    const int tid = threadIdx.x;
    const int r  = tid >> 4;          // 0..15
    const int c4 = (tid & 15) * 4;    // 0,4,..,60
    const int n0 = blockIdx.x * 64;
    const int k0 = blockIdx.y * 64;
    #pragma unroll
    for (int i = 0; i < 4; ++i) {
        const float4 v = *reinterpret_cast<const float4*>(&w[(size_t)(k0 + r + i * 16) * N + n0 + c4]);
        tile[r + i * 16][c4 + 0] = v.x;
        tile[r + i * 16][c4 + 1] = v.y;
        tile[r + i * 16][c4 + 2] = v.z;
        tile[r + i * 16][c4 + 3] = v.w;
    }
    __syncthreads();
    #pragma unroll
    for (int i = 0; i < 4; ++i) {
        ushort4 o;
        o.x = f32_bf16(tile[c4 + 0][r + i * 16]);
        o.y = f32_bf16(tile[c4 + 1][r + i * 16]);
        o.z = f32_bf16(tile[c4 + 2][r + i * 16]);
        o.w = f32_bf16(tile[c4 + 3][r + i * 16]);
        *reinterpret_cast<ushort4*>(&wt[(size_t)(n0 + r + i * 16) * 1024 + k0 + c4]) = o;
    }
}

// C = A[M][1024] @ Bt[N][1024]^T. m97 structure: 128x128 tile, BK=32,
// global_load_lds width=16 staging, 2 barriers/K-step, 4 waves x 64x64.
// MODE 0: scatter to Q (scaled), K, V^T(tiled) bf16. MODE 1: f32 out + bias.
template<int MODE>
__global__ __launch_bounds__(256) void gemm_bt(
    const ushort* __restrict__ A, const ushort* __restrict__ Bt,
    ushort* __restrict__ Qb, ushort* __restrict__ Kb, ushort* __restrict__ Vtb,
    float* __restrict__ Out, const float* __restrict__ bias)
{
    constexpr int K = 1024;
    __shared__ __align__(16) ushort As[128 * 32];
    __shared__ __align__(16) ushort Bs[128 * 32];

    const int lane = threadIdx.x & 63;
    const int w    = threadIdx.x >> 6;
    const int l16  = lane & 15;
    const int g    = lane >> 4;
    const int row0 = blockIdx.y * 128;
    const int col0 = blockIdx.x * 128;
    const int wr   = (w >> 1) * 64;
    const int wc   = (w & 1) * 64;

    // staging map: lane l of wave w -> tile row w*16 + l/4, k-col (l%4)*8
    const int srow = w * 16 + (lane >> 2);
    const int scol = (lane & 3) * 8;
    const ushort* Ag = A  + (size_t)(row0 + srow) * K + scol;
    const ushort* Bg = Bt + (size_t)(col0 + srow) * K + scol;
    ushort* AsW = As + w * (16 * 32);
    ushort* BsW = Bs + w * (16 * 32);

    f32x4 acc[4][4] = {};

    for (int kk = 0; kk < K; kk += 32) {
        gload16(Ag + kk,          AsW);
        gload16(Ag + 64 * K + kk, AsW + 64 * 32);
        gload16(Bg + kk,          BsW);
        gload16(Bg + 64 * K + kk, BsW + 64 * 32);
        __syncthreads();                       // drains vmcnt(0) then s_barrier
        bf16x8 a[4], b[4];
        #pragma unroll
        for (int m = 0; m < 4; ++m)
            a[m] = *reinterpret_cast<const bf16x8*>(&As[(wr + m * 16 + l16) * 32 + 8 * g]);
        #pragma unroll
        for (int n = 0; n < 4; ++n)
            b[n] = *reinterpret_cast<const bf16x8*>(&Bs[(wc + n * 16 + l16) * 32 + 8 * g]);
        #pragma unroll
        for (int m = 0; m < 4; ++m)
            #pragma unroll
            for (int n = 0; n < 4; ++n)
                acc[m][n] = __builtin_amdgcn_mfma_f32_16x16x32_bf16(a[m], b[n], acc[m][n], 0, 0, 0);
        __syncthreads();                       // before next stage overwrites LDS
    }

    if (MODE == 0) {
        const int part = col0 >> 10;                    // 0=Q 1=K 2=V (uniform per block)
        const float QSC = 0.18033688011112042f;         // DIM_HEAD^-0.5 * log2(e)
        #pragma unroll
        for (int m = 0; m < 4; ++m) {
            const int trow = row0 + wr + m * 16 + 4 * g;
            #pragma unroll
            for (int n = 0; n < 4; ++n) {
                const int c  = col0 + wc + n * 16 + l16;
                const int cc = c & 1023;
                const int h  = cc >> 6, d = cc & 63;
                #pragma unroll
                for (int jj = 0; jj < 4; ++jj) {
                    const int t  = trow + jj;
                    const int bb = t >> 11, nn = t & 2047;
                    const float v = acc[m][n][jj];
                    const size_t bhid = (size_t)(bb * NHEAD + h);
                    if (part == 0)
                        Qb[(bhid * NSEQ + nn) * DHEAD + d] = f32_bf16(v * QSC);
                    else if (part == 1)
                        Kb[(bhid * NSEQ + nn) * DHEAD + d] = f32_bf16(v);
                    else  // V^T tiled: [bh][n/32][d:64][n%32]
                        Vtb[bhid * (NSEQ * DHEAD) + (size_t)(nn >> 5) * (DHEAD * 32)
                            + d * 32 + (nn & 31)] = f32_bf16(v);
                }
            }
        }
    } else {
        #pragma unroll
        for (int m = 0; m < 4; ++m) {
            const int trow = row0 + wr + m * 16 + 4 * g;
            #pragma unroll
            for (int n = 0; n < 4; ++n) {
                const int c = col0 + wc + n * 16 + l16;
                const float bv = bias[c];
                #pragma unroll
                for (int jj = 0; jj < 4; ++jj)
                    Out[(size_t)(trow + jj) * DMODEL + c] = acc[m][n][jj] + bv;
            }
        }
    }
}

// QK^T (swapped) + online softmax for one 16-row q-tile against a 64-key LDS
// tile. Produces PV A-fragments pf0 (keys 0..31) / pf1 (keys 32..63) and
// rescales oacc. Lane(l16,g) holds S[key=16t+4g+jj][q=l16].
__device__ __forceinline__ void attn_qk(
    int kt, int qr0s, int l16, int g,
    const bf16x8 (&kk)[4][2],
    const bf16x8 qf0, const bf16x8 qf1,
    f32x4 (&oacc)[4], float& mrun, float& lsum,
    bf16x8& pf0, bf16x8& pf1)
{
    const f32x4 zero = {};
    f32x4 s[4];
    #pragma unroll
    for (int t = 0; t < 4; ++t) {
        s[t] = __builtin_amdgcn_mfma_f32_16x16x32_bf16(kk[t][0], qf0, zero, 0, 0, 0);
        s[t] = __builtin_amdgcn_mfma_f32_16x16x32_bf16(kk[t][1], qf1, s[t], 0, 0, 0);
    }
    if (kt + 63 > qr0s) {                               // diagonal tiles only
        const int kb = kt + 4 * g - (qr0s + l16);       // key - q = kb + 16t + jj
        #pragma unroll
        for (int t = 0; t < 4; ++t)
            #pragma unroll
            for (int jj = 0; jj < 4; ++jj)
                if (kb + 16 * t + jj > 0) s[t][jj] = -1e30f;
    }
    float mx = fmaxf(fmaxf(s[0][0], s[0][1]), fmaxf(s[0][2], s[0][3]));
    #pragma unroll
    for (int t = 1; t < 4; ++t)
        mx = fmaxf(mx, fmaxf(fmaxf(s[t][0], s[t][1]), fmaxf(s[t][2], s[t][3])));
    mx = fmaxf(mx, __shfl_xor(mx, 16));
    mx = fmaxf(mx, __shfl_xor(mx, 32));
    const float mn = fmaxf(mrun, mx);
    const float sc = __builtin_amdgcn_exp2f(mrun - mn);
    mrun = mn;
    float ps = 0.f;
    unsigned int pw[4][2];
    #pragma unroll
    for (int t = 0; t < 4; ++t) {
        const float p0 = __builtin_amdgcn_exp2f(s[t][0] - mn);
        const float p1 = __builtin_amdgcn_exp2f(s[t][1] - mn);
        const float p2 = __builtin_amdgcn_exp2f(s[t][2] - mn);
        const float p3 = __builtin_amdgcn_exp2f(s[t][3] - mn);
        ps += (p0 + p1) + (p2 + p3);
        pw[t][0] = cvt_pk_bf16(p0, p1);
        pw[t][1] = cvt_pk_bf16(p2, p3);
    }
    ps += __shfl_xor(ps, 16);
    ps += __shfl_xor(ps, 32);
    lsum = lsum * sc + ps;
    // relayout to PV A-fragment via permlane32/16 swaps
    unsigned int a0 = pw[0][0], a1 = pw[0][1], b0 = pw[1][0], b1 = pw[1][1];
    permlane32_swap(a0, b0); permlane32_swap(a1, b1);
    permlane16_swap(a0, b0); permlane16_swap(a1, b1);
    pf0 = __builtin_bit_cast(bf16x8, (uint32x4){a0, a1, b0, b1});
    unsigned int c0 = pw[2][0], c1 = pw[2][1], d0 = pw[3][0], d1 = pw[3][1];
    permlane32_swap(c0, d0); permlane32_swap(c1, d1);
    permlane16_swap(c0, d0); permlane16_swap(c1, d1);
    pf1 = __builtin_bit_cast(bf16x8, (uint32x4){c0, c1, d0, d1});
    // rescale O (sc at lane l16=q; oacc rows are q=4g+jj)
    float scj[4];
    #pragma unroll
    for (int jj = 0; jj < 4; ++jj) scj[jj] = __shfl(sc, 4 * g + jj);
    #pragma unroll
    for (int dt = 0; dt < 4; ++dt)
        #pragma unroll
        for (int jj = 0; jj < 4; ++jj) oacc[dt][jj] *= scj[jj];
}

// Causal flash attention. 1024 blocks (XCD-swizzled: all 16 q-blocks of one
// (b,h) on one XCD). 4 waves/block; each wave owns TWO 16-row q-tiles from
// complementary q-blocks {j, 31-j} (equal work: jhi+1 iters, lo active for
// t<=jlo). K/V 64-key tiles staged block-cooperatively into double-buffered
// LDS via global_load_lds; stage(t+1) issued before compute(t), drained by
// the end-of-iteration __syncthreads (2-phase pipeline).
__global__ __launch_bounds__(256) void attn_kernel(
    const ushort* __restrict__ Qb, const ushort* __restrict__ Kb,
    const ushort* __restrict__ Vt, ushort* __restrict__ Ob)
{
    // K tile: [2 d-halves][64 keys][32 d]  (64B rows -> conflict-free)
    // V tile: [2 k-halves][64 d][32 k]     (matches global tiled layout)
    __shared__ __align__(16) ushort Klds[2][4096];
    __shared__ __align__(16) ushort Vlds[2][4096];

    const int lane = threadIdx.x & 63;
    const int w    = threadIdx.x >> 6;
    const int l16  = lane & 15;
    const int g    = lane >> 4;

    const int bid = blockIdx.x;
    const int xcd = bid & 7, ii = bid >> 3;
    const int bh  = xcd * 8 + (ii >> 4);               // 8 (b,h) per XCD
    const int jlo = ii & 15;
    const int jhi = 31 - jlo;

    const int qr0_lo = jlo * 64 + w * 16;
    const int qr0_hi = jhi * 64 + w * 16;
    const int nt = jhi + 1;                            // 64-key tiles (uniform)

    const ushort* QpL = Qb + ((size_t)bh * NSEQ + qr0_lo + l16) * DHEAD + 8 * g;
    const ushort* QpH = Qb + ((size_t)bh * NSEQ + qr0_hi + l16) * DHEAD + 8 * g;
    const bf16x8 qfL0 = *reinterpret_cast<const bf16x8*>(QpL);
    const bf16x8 qfL1 = *reinterpret_cast<const bf16x8*>(QpL + 32);
    const bf16x8 qfH0 = *reinterpret_cast<const bf16x8*>(QpH);
    const bf16x8 qfH1 = *reinterpret_cast<const bf16x8*>(QpH + 32);

    const ushort* Kg = Kb + (size_t)bh * (NSEQ * DHEAD);
    const ushort* Vg = Vt + (size_t)bh * (NSEQ * DHEAD);

    // staging: wave w, issue i in {0,1} -> 512-elem chunk q = w*2+i of each tile
    const int q0   = w * 2;
    const int krow0 = (q0 & 3) * 16 + (lane >> 2);     // q and q+1 differ in row by 16
    const int kcol0 = (lane & 3) * 8;

    f32x4 oaccL[4] = {}, oaccH[4] = {};
    float mrunL = -1e30f, lsumL = 0.f, mrunH = -1e30f, lsumH = 0.f;

    // prologue: stage tile 0
    {
        const int kt = 0;
        #pragma unroll
        for (int i = 0; i < 2; ++i) {
            const int q = q0 + i;
            const int row = krow0 + i * 16;
            const int h = q >> 2;
            gload16(Kg + (size_t)(kt + ((q & 3) * 16 + (lane >> 2))) * 64 + h * 32 + kcol0,
                    &Klds[0][q * 512]);
            gload16(Vg + (size_t)kt * 64 + q * 512 + lane * 8,
                    &Vlds[0][q * 512]);
            (void)row;
        }
    }
    __syncthreads();

    for (int t = 0; t < nt; ++t) {
        const int cur = t & 1;
        if (t + 1 < nt) {
            const int kt1 = (t + 1) * 64;
            #pragma unroll
            for (int i = 0; i < 2; ++i) {
                const int q = q0 + i;
                const int h = q >> 2;
                gload16(Kg + (size_t)(kt1 + ((q & 3) * 16 + (lane >> 2))) * 64 + h * 32 + kcol0,
                        &Klds[cur ^ 1][q * 512]);
                gload16(Vg + (size_t)kt1 * 64 + q * 512 + lane * 8,
                        &Vlds[cur ^ 1][q * 512]);
            }
        }
        const int kt = t * 64;
        // K fragments from LDS
        bf16x8 kk[4][2];
        #pragma unroll
        for (int tt = 0; tt < 4; ++tt) {
            #pragma unroll
            for (int h = 0; h < 2; ++h)
                kk[tt][h] = *reinterpret_cast<const bf16x8*>(
                    &Klds[cur][h * 2048 + (16 * tt + l16) * 32 + 8 * g]);
        }
        bf16x8 pfH0, pfH1, pfL0, pfL1;
        attn_qk(kt, qr0_hi, l16, g, kk, qfH0, qfH1, oaccH, mrunH, lsumH, pfH0, pfH1);
        const bool doLo = (t <= jlo);
        if (doLo)
            attn_qk(kt, qr0_lo, l16, g, kk, qfL0, qfL1, oaccL, mrunL, lsumL, pfL0, pfL1);
        // PV: V fragments from LDS, shared by hi/lo
        #pragma unroll
        for (int dt = 0; dt < 4; ++dt) {
            const bf16x8 v0 = *reinterpret_cast<const bf16x8*>(
                &Vlds[cur][(dt * 16 + l16) * 32 + 8 * g]);
            const bf16x8 v1 = *reinterpret_cast<const bf16x8*>(
                &Vlds[cur][2048 + (dt * 16 + l16) * 32 + 8 * g]);
            oaccH[dt] = __builtin_amdgcn_mfma_f32_16x16x32_bf16(pfH0, v0, oaccH[dt], 0, 0, 0);
            oaccH[dt] = __builtin_amdgcn_mfma_f32_16x16x32_bf16(pfH1, v1, oaccH[dt], 0, 0, 0);
            if (doLo) {
                oaccL[dt] = __builtin_amdgcn_mfma_f32_16x16x32_bf16(pfL0, v0, oaccL[dt], 0, 0, 0);
                oaccL[dt] = __builtin_amdgcn_mfma_f32_16x16x32_bf16(pfL1, v1, oaccL[dt], 0, 0, 0);
            }
        }
        __syncthreads();                               // drain stage + protect bufs
    }

    const int bb = bh >> 4, h = bh & 15;
    {
        const float inv = 1.0f / lsumH;
        float invj[4];
        #pragma unroll
        for (int jj = 0; jj < 4; ++jj) invj[jj] = __shfl(inv, 4 * g + jj);
        #pragma unroll
        for (int jj = 0; jj < 4; ++jj) {
            const size_t t = (size_t)bb * NSEQ + qr0_hi + 4 * g + jj;
            #pragma unroll
            for (int dt = 0; dt < 4; ++dt)
                Ob[t * DMODEL + h * DHEAD + dt * 16 + l16] = f32_bf16(oaccH[dt][jj] * invj[jj]);
        }
    }
    {
        const float inv = 1.0f / lsumL;
        float invj[4];
        #pragma unroll
        for (int jj = 0; jj < 4; ++jj) invj[jj] = __shfl(inv, 4 * g + jj);
        #pragma unroll
        for (int jj = 0; jj < 4; ++jj) {
            const size_t t = (size_t)bb * NSEQ + qr0_lo + 4 * g + jj;
            #pragma unroll
            for (int dt = 0; dt < 4; ++dt)
                Ob[t * DMODEL + h * DHEAD + dt * 16 + l16] = f32_bf16(oaccL[dt][jj] * invj[jj]);
        }
    }
}

extern "C" void kernel_launch(void* const* d_in, const int* in_sizes, int n_in,
                              void* d_out, int out_size, void* d_ws, size_t ws_size,
                              hipStream_t stream)
{
    const float* x     = (const float*)d_in[0];
    const float* w_qkv = (const float*)d_in[1];
    const float* w_out = (const float*)d_in[2];
    const float* b_out = (const float*)d_in[3];
    float* out = (float*)d_out;

    char* ws = (char*)d_ws;
    // workspace layout (bytes); total 75,497,472
    ushort* x_bf   = (ushort*)(ws);                    // 16,777,216  (reused as attn out)
    ushort* wqkv_t = (ushort*)(ws + 16777216);         //  6,291,456
    ushort* wout_t = (ushort*)(ws + 23068672);         //  2,097,152
    ushort* q_bf   = (ushort*)(ws + 25165824);         // 16,777,216
    ushort* k_bf   = (ushort*)(ws + 41943040);         // 16,777,216
    ushort* vt_bf  = (ushort*)(ws + 58720256);         // 16,777,216 (V^T tiled)
    ushort* attn_bf = x_bf;                            // alias: x_bf dead after QKV GEMM

    cvt_x_kernel<<<dim3(TOKENS * DMODEL / 4 / 256), dim3(256), 0, stream>>>(x, x_bf);
    cvt_wt_kernel<<<dim3(NQKV / 64, 1024 / 64), dim3(256), 0, stream>>>(w_qkv, wqkv_t, NQKV);
    cvt_wt_kernel<<<dim3(1024 / 64, 1024 / 64), dim3(256), 0, stream>>>(w_out, wout_t, 1024);

    gemm_bt<0><<<dim3(NQKV / 128, TOKENS / 128), dim3(256), 0, stream>>>(
        x_bf, wqkv_t, q_bf, k_bf, vt_bf, nullptr, nullptr);

    attn_kernel<<<dim3(1024), dim3(256), 0, stream>>>(q_bf, k_bf, vt_bf, attn_bf);

    gemm_bt<1><<<dim3(DMODEL / 128, TOKENS / 128), dim3(256), 0, stream>>>(
        attn_bf, wout_t, nullptr, nullptr, nullptr, out, b_out);
}

// Round 7
// 215.943 us; speedup vs baseline: 3.4251x; 1.0404x over previous
//
#include <hip/hip_runtime.h>
#include <hip/hip_bf16.h>
#include <stdint.h>

typedef __attribute__((ext_vector_type(8))) short bf16x8;
typedef __attribute__((ext_vector_type(4))) float f32x4;
typedef __attribute__((ext_vector_type(4))) unsigned int uint32x4;

#define TOKENS 8192
#define DMODEL 1024
#define NQKV   3072
#define NSEQ   2048
#define NHEAD  16
#define DHEAD  64

__device__ __forceinline__ ushort f32_bf16(float f) {
    uint32_t u = __builtin_bit_cast(uint32_t, f);
    u = (u + 0x7fffu + ((u >> 16) & 1u)) >> 16;
    return (ushort)u;
}

__device__ __forceinline__ unsigned int cvt_pk_bf16(float lo, float hi) {
    unsigned int r;
    asm("v_cvt_pk_bf16_f32 %0, %1, %2" : "=v"(r) : "v"(lo), "v"(hi));
    return r;
}
__device__ __forceinline__ void permlane32_swap(unsigned int& a, unsigned int& b) {
    asm("v_permlane32_swap_b32 %0, %1" : "+v"(a), "+v"(b));
}
__device__ __forceinline__ void permlane16_swap(unsigned int& a, unsigned int& b) {
    asm("v_permlane16_swap_b32 %0, %1" : "+v"(a), "+v"(b));
}
// Opaque register copy: NOT a COPY MachineInstr, so the register coalescer
// cannot merge dst with src. Needed before permlane*_swap when both operands
// would otherwise be copy-related (same value) -> same physical register ->
// self-swap (row rotation) instead of a cross-register swap. [R6 post-mortem]
__device__ __forceinline__ unsigned opaque_copy(unsigned x) {
    unsigned y;
    asm("v_mov_b32 %0, %1" : "=v"(y) : "v"(x));
    return y;
}

// cross-lane reduce over lanes {l, l^16, l^32, l^48} via permlane swaps (VALU,
// no LDS pipe). With b an (opaque) copy of a, after permlane16_swap:
// a={x.r0,x.r0,x.r2,x.r2}, b={x.r1,x.r1,x.r3,x.r3} -> fmax gives max(x[l],x[l^16]).
__device__ __forceinline__ float red_max_g(float x) {
    unsigned a = __builtin_bit_cast(unsigned, x);
    unsigned b = opaque_copy(a);
    permlane16_swap(a, b);
    float r = fmaxf(__builtin_bit_cast(float, a), __builtin_bit_cast(float, b));
    unsigned c = __builtin_bit_cast(unsigned, r);
    unsigned d = opaque_copy(c);
    permlane32_swap(c, d);
    return fmaxf(__builtin_bit_cast(float, c), __builtin_bit_cast(float, d));
}
__device__ __forceinline__ float red_sum_g(float x) {
    unsigned a = __builtin_bit_cast(unsigned, x);
    unsigned b = opaque_copy(a);
    permlane16_swap(a, b);
    float r = __builtin_bit_cast(float, a) + __builtin_bit_cast(float, b);
    unsigned c = __builtin_bit_cast(unsigned, r);
    unsigned d = opaque_copy(c);
    permlane32_swap(c, d);
    return __builtin_bit_cast(float, c) + __builtin_bit_cast(float, d);
}

// async global->LDS, 16B per lane; LDS dest = wave-uniform base + lane*16
__device__ __forceinline__ void gload16(const void* g, void* l) {
    __builtin_amdgcn_global_load_lds(
        (const __attribute__((address_space(1))) void*)g,
        (__attribute__((address_space(3))) void*)l, 16, 0, 0);
}

// x [8192][1024] f32 -> bf16 (vectorized by 4)
__global__ void cvt_x_kernel(const float* __restrict__ x, ushort* __restrict__ xb) {
    int i = blockIdx.x * 256 + threadIdx.x;
    float4 v = reinterpret_cast<const float4*>(x)[i];
    ushort4 o;
    o.x = f32_bf16(v.x); o.y = f32_bf16(v.y);
    o.z = f32_bf16(v.z); o.w = f32_bf16(v.w);
    reinterpret_cast<ushort4*>(xb)[i] = o;
}

// w [1024][N] f32 -> wt [N][1024] bf16 via 64x64 LDS tile (both sides coalesced)
__global__ __launch_bounds__(256) void cvt_wt_kernel(
    const float* __restrict__ w, ushort* __restrict__ wt, int N)
{
    __shared__ float tile[64][65];
    const int tid = threadIdx.x;
    const int r  = tid >> 4;          // 0..15
    const int c4 = (tid & 15) * 4;    // 0,4,..,60
    const int n0 = blockIdx.x * 64;
    const int k0 = blockIdx.y * 64;
    #pragma unroll
    for (int i = 0; i < 4; ++i) {
        const float4 v = *reinterpret_cast<const float4*>(&w[(size_t)(k0 + r + i * 16) * N + n0 + c4]);
        tile[r + i * 16][c4 + 0] = v.x;
        tile[r + i * 16][c4 + 1] = v.y;
        tile[r + i * 16][c4 + 2] = v.z;
        tile[r + i * 16][c4 + 3] = v.w;
    }
    __syncthreads();
    #pragma unroll
    for (int i = 0; i < 4; ++i) {
        ushort4 o;
        o.x = f32_bf16(tile[c4 + 0][r + i * 16]);
        o.y = f32_bf16(tile[c4 + 1][r + i * 16]);
        o.z = f32_bf16(tile[c4 + 2][r + i * 16]);
        o.w = f32_bf16(tile[c4 + 3][r + i * 16]);
        *reinterpret_cast<ushort4*>(&wt[(size_t)(n0 + r + i * 16) * 1024 + k0 + c4]) = o;
    }
}

// C = A[M][1024] @ Bt[N][1024]^T. m97 structure: 128x128 tile, BK=32,
// global_load_lds width=16 staging, 2 barriers/K-step, 4 waves x 64x64.
// MODE 0: scatter to Q (scaled), K, V^T(tiled) bf16. MODE 1: f32 out + bias.
template<int MODE>
__global__ __launch_bounds__(256) void gemm_bt(
    const ushort* __restrict__ A, const ushort* __restrict__ Bt,
    ushort* __restrict__ Qb, ushort* __restrict__ Kb, ushort* __restrict__ Vtb,
    float* __restrict__ Out, const float* __restrict__ bias)
{
    constexpr int K = 1024;
    __shared__ __align__(16) ushort As[128 * 32];
    __shared__ __align__(16) ushort Bs[128 * 32];

    const int lane = threadIdx.x & 63;
    const int w    = threadIdx.x >> 6;
    const int l16  = lane & 15;
    const int g    = lane >> 4;
    const int row0 = blockIdx.y * 128;
    const int col0 = blockIdx.x * 128;
    const int wr   = (w >> 1) * 64;
    const int wc   = (w & 1) * 64;

    // staging map: lane l of wave w -> tile row w*16 + l/4, k-col (l%4)*8
    const int srow = w * 16 + (lane >> 2);
    const int scol = (lane & 3) * 8;
    const ushort* Ag = A  + (size_t)(row0 + srow) * K + scol;
    const ushort* Bg = Bt + (size_t)(col0 + srow) * K + scol;
    ushort* AsW = As + w * (16 * 32);
    ushort* BsW = Bs + w * (16 * 32);

    f32x4 acc[4][4] = {};

    for (int kk = 0; kk < K; kk += 32) {
        gload16(Ag + kk,          AsW);
        gload16(Ag + 64 * K + kk, AsW + 64 * 32);
        gload16(Bg + kk,          BsW);
        gload16(Bg + 64 * K + kk, BsW + 64 * 32);
        __syncthreads();                       // drains vmcnt(0) then s_barrier
        bf16x8 a[4], b[4];
        #pragma unroll
        for (int m = 0; m < 4; ++m)
            a[m] = *reinterpret_cast<const bf16x8*>(&As[(wr + m * 16 + l16) * 32 + 8 * g]);
        #pragma unroll
        for (int n = 0; n < 4; ++n)
            b[n] = *reinterpret_cast<const bf16x8*>(&Bs[(wc + n * 16 + l16) * 32 + 8 * g]);
        #pragma unroll
        for (int m = 0; m < 4; ++m)
            #pragma unroll
            for (int n = 0; n < 4; ++n)
                acc[m][n] = __builtin_amdgcn_mfma_f32_16x16x32_bf16(a[m], b[n], acc[m][n], 0, 0, 0);
        __syncthreads();                       // before next stage overwrites LDS
    }

    if (MODE == 0) {
        const int part = col0 >> 10;                    // 0=Q 1=K 2=V (uniform per block)
        const float QSC = 0.18033688011112042f;         // DIM_HEAD^-0.5 * log2(e)
        #pragma unroll
        for (int m = 0; m < 4; ++m) {
            const int trow = row0 + wr + m * 16 + 4 * g;
            #pragma unroll
            for (int n = 0; n < 4; ++n) {
                const int c  = col0 + wc + n * 16 + l16;
                const int cc = c & 1023;
                const int h  = cc >> 6, d = cc & 63;
                #pragma unroll
                for (int jj = 0; jj < 4; ++jj) {
                    const int t  = trow + jj;
                    const int bb = t >> 11, nn = t & 2047;
                    const float v = acc[m][n][jj];
                    const size_t bhid = (size_t)(bb * NHEAD + h);
                    if (part == 0)
                        Qb[(bhid * NSEQ + nn) * DHEAD + d] = f32_bf16(v * QSC);
                    else if (part == 1)
                        Kb[(bhid * NSEQ + nn) * DHEAD + d] = f32_bf16(v);
                    else  // V^T tiled: [bh][n/32][d:64][n%32]
                        Vtb[bhid * (NSEQ * DHEAD) + (size_t)(nn >> 5) * (DHEAD * 32)
                            + d * 32 + (nn & 31)] = f32_bf16(v);
                }
            }
        }
    } else {
        #pragma unroll
        for (int m = 0; m < 4; ++m) {
            const int trow = row0 + wr + m * 16 + 4 * g;
            #pragma unroll
            for (int n = 0; n < 4; ++n) {
                const int c = col0 + wc + n * 16 + l16;
                const float bv = bias[c];
                #pragma unroll
                for (int jj = 0; jj < 4; ++jj)
                    Out[(size_t)(trow + jj) * DMODEL + c] = acc[m][n][jj] + bv;
            }
        }
    }
}

// QK^T (swapped) + online softmax for one 16-row q-tile against a 64-key LDS
// tile. Lane(l16,g) holds S[key=16t+4g+jj][q=l16]. Permlane reductions (no
// ds_bpermute); defer-rescale with THR=8 (P bounded by 2^8, bf16-safe).
__device__ __forceinline__ void attn_qk(
    int kt, int qr0s, int l16, int g,
    const bf16x8 (&kk)[4][2],
    const bf16x8 qf0, const bf16x8 qf1,
    f32x4 (&oacc)[4], float& mrun, float& lsum,
    bf16x8& pf0, bf16x8& pf1)
{
    const f32x4 zero = {};
    f32x4 s[4];
    #pragma unroll
    for (int t = 0; t < 4; ++t) {
        s[t] = __builtin_amdgcn_mfma_f32_16x16x32_bf16(kk[t][0], qf0, zero, 0, 0, 0);
        s[t] = __builtin_amdgcn_mfma_f32_16x16x32_bf16(kk[t][1], qf1, s[t], 0, 0, 0);
    }
    if (kt + 63 > qr0s) {                               // diagonal tiles only
        const int kb = kt + 4 * g - (qr0s + l16);       // key - q = kb + 16t + jj
        #pragma unroll
        for (int t = 0; t < 4; ++t)
            #pragma unroll
            for (int jj = 0; jj < 4; ++jj)
                if (kb + 16 * t + jj > 0) s[t][jj] = -1e30f;
    }
    // in-lane max tree shaped for v_max3 fusion (16 values -> 8 ops)
    const float m0 = fmaxf(fmaxf(s[0][0], s[0][1]), s[0][2]);
    const float m1 = fmaxf(fmaxf(s[0][3], s[1][0]), s[1][1]);
    const float m2 = fmaxf(fmaxf(s[1][2], s[1][3]), s[2][0]);
    const float m3 = fmaxf(fmaxf(s[2][1], s[2][2]), s[2][3]);
    const float m4 = fmaxf(fmaxf(s[3][0], s[3][1]), s[3][2]);
    const float m5 = fmaxf(fmaxf(m0, m1), m2);
    const float m6 = fmaxf(fmaxf(m3, m4), s[3][3]);
    float mx = red_max_g(fmaxf(m5, m6));
    // defer-rescale: only when some row grew past mrun + 8
    if (__any(mx > mrun + 8.0f)) {
        const float mn = fmaxf(mrun, mx);
        const float sc = __builtin_amdgcn_exp2f(mrun - mn);
        mrun = mn;
        lsum *= sc;
        float scj[4];
        #pragma unroll
        for (int jj = 0; jj < 4; ++jj) scj[jj] = __shfl(sc, 4 * g + jj);
        #pragma unroll
        for (int dt = 0; dt < 4; ++dt)
            #pragma unroll
            for (int jj = 0; jj < 4; ++jj) oacc[dt][jj] *= scj[jj];
    }
    float ps = 0.f;
    unsigned int pw[4][2];
    #pragma unroll
    for (int t = 0; t < 4; ++t) {
        const float p0 = __builtin_amdgcn_exp2f(s[t][0] - mrun);
        const float p1 = __builtin_amdgcn_exp2f(s[t][1] - mrun);
        const float p2 = __builtin_amdgcn_exp2f(s[t][2] - mrun);
        const float p3 = __builtin_amdgcn_exp2f(s[t][3] - mrun);
        ps += (p0 + p1) + (p2 + p3);
        pw[t][0] = cvt_pk_bf16(p0, p1);
        pw[t][1] = cvt_pk_bf16(p2, p3);
    }
    lsum += red_sum_g(ps);
    // relayout to PV A-fragment via permlane32/16 swaps (operands here are
    // distinct defs -> no coalescing hazard)
    unsigned int a0 = pw[0][0], a1 = pw[0][1], b0 = pw[1][0], b1 = pw[1][1];
    permlane32_swap(a0, b0); permlane32_swap(a1, b1);
    permlane16_swap(a0, b0); permlane16_swap(a1, b1);
    pf0 = __builtin_bit_cast(bf16x8, (uint32x4){a0, a1, b0, b1});
    unsigned int c0 = pw[2][0], c1 = pw[2][1], d0 = pw[3][0], d1 = pw[3][1];
    permlane32_swap(c0, d0); permlane32_swap(c1, d1);
    permlane16_swap(c0, d0); permlane16_swap(c1, d1);
    pf1 = __builtin_bit_cast(bf16x8, (uint32x4){c0, c1, d0, d1});
}

// Causal flash attention. 1024 blocks (XCD-swizzled: all 16 q-blocks of one
// (b,h) on one XCD). 4 waves/block; each wave owns TWO 16-row q-tiles from
// complementary q-blocks {j, 31-j} (equal work: jhi+1 iters, lo active for
// t<=jlo). K/V 64-key tiles staged block-cooperatively into double-buffered
// LDS via global_load_lds; stage(t+1) issued before compute(t), drained by
// the end-of-iteration __syncthreads (2-phase pipeline).
__global__ __launch_bounds__(256) void attn_kernel(
    const ushort* __restrict__ Qb, const ushort* __restrict__ Kb,
    const ushort* __restrict__ Vt, ushort* __restrict__ Ob)
{
    // K tile: [2 d-halves][64 keys][32 d]  (64B rows -> conflict-free)
    // V tile: [2 k-halves][64 d][32 k]     (matches global tiled layout)
    __shared__ __align__(16) ushort Klds[2][4096];
    __shared__ __align__(16) ushort Vlds[2][4096];

    const int lane = threadIdx.x & 63;
    const int w    = threadIdx.x >> 6;
    const int l16  = lane & 15;
    const int g    = lane >> 4;

    const int bid = blockIdx.x;
    const int xcd = bid & 7, ii = bid >> 3;
    const int bh  = xcd * 8 + (ii >> 4);               // 8 (b,h) per XCD
    const int jlo = ii & 15;
    const int jhi = 31 - jlo;

    const int qr0_lo = jlo * 64 + w * 16;
    const int qr0_hi = jhi * 64 + w * 16;
    const int nt = jhi + 1;                            // 64-key tiles

    const ushort* QpL = Qb + ((size_t)bh * NSEQ + qr0_lo + l16) * DHEAD + 8 * g;
    const ushort* QpH = Qb + ((size_t)bh * NSEQ + qr0_hi + l16) * DHEAD + 8 * g;
    const bf16x8 qfL0 = *reinterpret_cast<const bf16x8*>(QpL);
    const bf16x8 qfL1 = *reinterpret_cast<const bf16x8*>(QpL + 32);
    const bf16x8 qfH0 = *reinterpret_cast<const bf16x8*>(QpH);
    const bf16x8 qfH1 = *reinterpret_cast<const bf16x8*>(QpH + 32);

    const ushort* Kg = Kb + (size_t)bh * (NSEQ * DHEAD);
    const ushort* Vg = Vt + (size_t)bh * (NSEQ * DHEAD);

    // staging: wave w, issue i in {0,1} -> 512-elem chunk q = w*2+i of each tile
    const int q0   = w * 2;
    const int kcol0 = (lane & 3) * 8;

    f32x4 oaccL[4] = {}, oaccH[4] = {};
    float mrunL = -1e30f, lsumL = 0.f, mrunH = -1e30f, lsumH = 0.f;

    // prologue: stage tile 0
    {
        #pragma unroll
        for (int i = 0; i < 2; ++i) {
            const int q = q0 + i;
            const int h = q >> 2;
            gload16(Kg + (size_t)((q & 3) * 16 + (lane >> 2)) * 64 + h * 32 + kcol0,
                    &Klds[0][q * 512]);
            gload16(Vg + (size_t)q * 512 + lane * 8,
                    &Vlds[0][q * 512]);
        }
    }
    __syncthreads();

    for (int t = 0; t < nt; ++t) {
        const int cur = t & 1;
        if (t + 1 < nt) {
            const int kt1 = (t + 1) * 64;
            #pragma unroll
            for (int i = 0; i < 2; ++i) {
                const int q = q0 + i;
                const int h = q >> 2;
                gload16(Kg + (size_t)(kt1 + ((q & 3) * 16 + (lane >> 2))) * 64 + h * 32 + kcol0,
                        &Klds[cur ^ 1][q * 512]);
                gload16(Vg + (size_t)kt1 * 64 + q * 512 + lane * 8,
                        &Vlds[cur ^ 1][q * 512]);
            }
        }
        const int kt = t * 64;
        // K fragments from LDS
        bf16x8 kk[4][2];
        #pragma unroll
        for (int tt = 0; tt < 4; ++tt) {
            #pragma unroll
            for (int h = 0; h < 2; ++h)
                kk[tt][h] = *reinterpret_cast<const bf16x8*>(
                    &Klds[cur][h * 2048 + (16 * tt + l16) * 32 + 8 * g]);
        }
        bf16x8 pfH0, pfH1, pfL0, pfL1;
        attn_qk(kt, qr0_hi, l16, g, kk, qfH0, qfH1, oaccH, mrunH, lsumH, pfH0, pfH1);
        const bool doLo = (t <= jlo);
        if (doLo)
            attn_qk(kt, qr0_lo, l16, g, kk, qfL0, qfL1, oaccL, mrunL, lsumL, pfL0, pfL1);
        // PV: V fragments from LDS, shared by hi/lo
        #pragma unroll
        for (int dt = 0; dt < 4; ++dt) {
            const bf16x8 v0 = *reinterpret_cast<const bf16x8*>(
                &Vlds[cur][(dt * 16 + l16) * 32 + 8 * g]);
            const bf16x8 v1 = *reinterpret_cast<const bf16x8*>(
                &Vlds[cur][2048 + (dt * 16 + l16) * 32 + 8 * g]);
            oaccH[dt] = __builtin_amdgcn_mfma_f32_16x16x32_bf16(pfH0, v0, oaccH[dt], 0, 0, 0);
            oaccH[dt] = __builtin_amdgcn_mfma_f32_16x16x32_bf16(pfH1, v1, oaccH[dt], 0, 0, 0);
            if (doLo) {
                oaccL[dt] = __builtin_amdgcn_mfma_f32_16x16x32_bf16(pfL0, v0, oaccL[dt], 0, 0, 0);
                oaccL[dt] = __builtin_amdgcn_mfma_f32_16x16x32_bf16(pfL1, v1, oaccL[dt], 0, 0, 0);
            }
        }
        __syncthreads();                               // drain stage + protect bufs
    }

    const int bb = bh >> 4, h = bh & 15;
    {
        const float inv = 1.0f / lsumH;
        float invj[4];
        #pragma unroll
        for (int jj = 0; jj < 4; ++jj) invj[jj] = __shfl(inv, 4 * g + jj);
        #pragma unroll
        for (int jj = 0; jj < 4; ++jj) {
            const size_t t = (size_t)bb * NSEQ + qr0_hi + 4 * g + jj;
            #pragma unroll
            for (int dt = 0; dt < 4; ++dt)
                Ob[t * DMODEL + h * DHEAD + dt * 16 + l16] = f32_bf16(oaccH[dt][jj] * invj[jj]);
        }
    }
    {
        const float inv = 1.0f / lsumL;
        float invj[4];
        #pragma unroll
        for (int jj = 0; jj < 4; ++jj) invj[jj] = __shfl(inv, 4 * g + jj);
        #pragma unroll
        for (int jj = 0; jj < 4; ++jj) {
            const size_t t = (size_t)bb * NSEQ + qr0_lo + 4 * g + jj;
            #pragma unroll
            for (int dt = 0; dt < 4; ++dt)
                Ob[t * DMODEL + h * DHEAD + dt * 16 + l16] = f32_bf16(oaccL[dt][jj] * invj[jj]);
        }
    }
}

extern "C" void kernel_launch(void* const* d_in, const int* in_sizes, int n_in,
                              void* d_out, int out_size, void* d_ws, size_t ws_size,
                              hipStream_t stream)
{
    const float* x     = (const float*)d_in[0];
    const float* w_qkv = (const float*)d_in[1];
    const float* w_out = (const float*)d_in[2];
    const float* b_out = (const float*)d_in[3];
    float* out = (float*)d_out;

    char* ws = (char*)d_ws;
    // workspace layout (bytes); total 75,497,472
    ushort* x_bf   = (ushort*)(ws);                    // 16,777,216  (reused as attn out)
    ushort* wqkv_t = (ushort*)(ws + 16777216);         //  6,291,456
    ushort* wout_t = (ushort*)(ws + 23068672);         //  2,097,152
    ushort* q_bf   = (ushort*)(ws + 25165824);         // 16,777,216
    ushort* k_bf   = (ushort*)(ws + 41943040);         // 16,777,216
    ushort* vt_bf  = (ushort*)(ws + 58720256);         // 16,777,216 (V^T tiled)
    ushort* attn_bf = x_bf;                            // alias: x_bf dead after QKV GEMM

    cvt_x_kernel<<<dim3(TOKENS * DMODEL / 4 / 256), dim3(256), 0, stream>>>(x, x_bf);
    cvt_wt_kernel<<<dim3(NQKV / 64, 1024 / 64), dim3(256), 0, stream>>>(w_qkv, wqkv_t, NQKV);
    cvt_wt_kernel<<<dim3(1024 / 64, 1024 / 64), dim3(256), 0, stream>>>(w_out, wout_t, 1024);

    gemm_bt<0><<<dim3(NQKV / 128, TOKENS / 128), dim3(256), 0, stream>>>(
        x_bf, wqkv_t, q_bf, k_bf, vt_bf, nullptr, nullptr);

    attn_kernel<<<dim3(1024), dim3(256), 0, stream>>>(q_bf, k_bf, vt_bf, attn_bf);

    gemm_bt<1><<<dim3(DMODEL / 128, TOKENS / 128), dim3(256), 0, stream>>>(
        attn_bf, wout_t, nullptr, nullptr, nullptr, out, b_out);
}

// Round 8
// 214.914 us; speedup vs baseline: 3.4415x; 1.0048x over previous
//
#include <hip/hip_runtime.h>
#include <hip/hip_bf16.h>
#include <stdint.h>

typedef __attribute__((ext_vector_type(8))) short bf16x8;
typedef __attribute__((ext_vector_type(4))) float f32x4;
typedef __attribute__((ext_vector_type(4))) unsigned int uint32x4;

#define TOKENS 8192
#define DMODEL 1024
#define NQKV   3072
#define NSEQ   2048
#define NHEAD  16
#define DHEAD  64

// ---- LDS 64B-row XOR swizzle (T2 adapted) -------------------------------
// LDS tiles are [row][32 ushort] = 64B rows. ds_read_b128 at (row=l16, quad=g)
// batches 8 even rows onto one 4-bank quad per quarter-wave (8-way). Swizzle
// quad' = quad ^ ((row>>1)&3) spreads them (2/quad = minimal). Staged via
// linear global_load_lds dest + inverse-swizzled per-lane global SOURCE
// (rule #21); read side applies the same XOR. For reads, all row offsets are
// multiples of 8 rows, so quad' = g ^ ((l16>>1)&3), uniform per lane.

__device__ __forceinline__ ushort f32_bf16(float f) {
    uint32_t u = __builtin_bit_cast(uint32_t, f);
    u = (u + 0x7fffu + ((u >> 16) & 1u)) >> 16;
    return (ushort)u;
}

__device__ __forceinline__ unsigned int cvt_pk_bf16(float lo, float hi) {
    unsigned int r;
    asm("v_cvt_pk_bf16_f32 %0, %1, %2" : "=v"(r) : "v"(lo), "v"(hi));
    return r;
}
__device__ __forceinline__ void permlane32_swap(unsigned int& a, unsigned int& b) {
    asm("v_permlane32_swap_b32 %0, %1" : "+v"(a), "+v"(b));
}
__device__ __forceinline__ void permlane16_swap(unsigned int& a, unsigned int& b) {
    asm("v_permlane16_swap_b32 %0, %1" : "+v"(a), "+v"(b));
}
// Opaque register copy: NOT a COPY MachineInstr, so the register coalescer
// cannot merge dst with src (else permlane*_swap self-swaps). [R6 post-mortem]
__device__ __forceinline__ unsigned opaque_copy(unsigned x) {
    unsigned y;
    asm("v_mov_b32 %0, %1" : "=v"(y) : "v"(x));
    return y;
}

// cross-lane reduce over lanes {l, l^16, l^32, l^48} via permlane swaps
__device__ __forceinline__ float red_max_g(float x) {
    unsigned a = __builtin_bit_cast(unsigned, x);
    unsigned b = opaque_copy(a);
    permlane16_swap(a, b);
    float r = fmaxf(__builtin_bit_cast(float, a), __builtin_bit_cast(float, b));
    unsigned c = __builtin_bit_cast(unsigned, r);
    unsigned d = opaque_copy(c);
    permlane32_swap(c, d);
    return fmaxf(__builtin_bit_cast(float, c), __builtin_bit_cast(float, d));
}
__device__ __forceinline__ float red_sum_g(float x) {
    unsigned a = __builtin_bit_cast(unsigned, x);
    unsigned b = opaque_copy(a);
    permlane16_swap(a, b);
    float r = __builtin_bit_cast(float, a) + __builtin_bit_cast(float, b);
    unsigned c = __builtin_bit_cast(unsigned, r);
    unsigned d = opaque_copy(c);
    permlane32_swap(c, d);
    return __builtin_bit_cast(float, c) + __builtin_bit_cast(float, d);
}

// async global->LDS, 16B per lane; LDS dest = wave-uniform base + lane*16
__device__ __forceinline__ void gload16(const void* g, void* l) {
    __builtin_amdgcn_global_load_lds(
        (const __attribute__((address_space(1))) void*)g,
        (__attribute__((address_space(3))) void*)l, 16, 0, 0);
}

// x [8192][1024] f32 -> bf16 (vectorized by 4)
__global__ void cvt_x_kernel(const float* __restrict__ x, ushort* __restrict__ xb) {
    int i = blockIdx.x * 256 + threadIdx.x;
    float4 v = reinterpret_cast<const float4*>(x)[i];
    ushort4 o;
    o.x = f32_bf16(v.x); o.y = f32_bf16(v.y);
    o.z = f32_bf16(v.z); o.w = f32_bf16(v.w);
    reinterpret_cast<ushort4*>(xb)[i] = o;
}

// w [1024][N] f32 -> wt [N][1024] bf16 via 64x64 LDS tile (both sides coalesced)
__global__ __launch_bounds__(256) void cvt_wt_kernel(
    const float* __restrict__ w, ushort* __restrict__ wt, int N)
{
    __shared__ float tile[64][65];
    const int tid = threadIdx.x;
    const int r  = tid >> 4;          // 0..15
    const int c4 = (tid & 15) * 4;    // 0,4,..,60
    const int n0 = blockIdx.x * 64;
    const int k0 = blockIdx.y * 64;
    #pragma unroll
    for (int i = 0; i < 4; ++i) {
        const float4 v = *reinterpret_cast<const float4*>(&w[(size_t)(k0 + r + i * 16) * N + n0 + c4]);
        tile[r + i * 16][c4 + 0] = v.x;
        tile[r + i * 16][c4 + 1] = v.y;
        tile[r + i * 16][c4 + 2] = v.z;
        tile[r + i * 16][c4 + 3] = v.w;
    }
    __syncthreads();
    #pragma unroll
    for (int i = 0; i < 4; ++i) {
        ushort4 o;
        o.x = f32_bf16(tile[c4 + 0][r + i * 16]);
        o.y = f32_bf16(tile[c4 + 1][r + i * 16]);
        o.z = f32_bf16(tile[c4 + 2][r + i * 16]);
        o.w = f32_bf16(tile[c4 + 3][r + i * 16]);
        *reinterpret_cast<ushort4*>(&wt[(size_t)(n0 + r + i * 16) * 1024 + k0 + c4]) = o;
    }
}

// C = A[M][1024] @ Bt[N][1024]^T. m97 structure: 128x128 tile, BK=32,
// global_load_lds width=16 staging (swizzled source), 2 barriers/K-step.
// MODE 0: scatter to Q (scaled), K, V^T(tiled) bf16. MODE 1: f32 out + bias.
template<int MODE>
__global__ __launch_bounds__(256) void gemm_bt(
    const ushort* __restrict__ A, const ushort* __restrict__ Bt,
    ushort* __restrict__ Qb, ushort* __restrict__ Kb, ushort* __restrict__ Vtb,
    float* __restrict__ Out, const float* __restrict__ bias)
{
    constexpr int K = 1024;
    __shared__ __align__(16) ushort As[128 * 32];
    __shared__ __align__(16) ushort Bs[128 * 32];

    const int lane = threadIdx.x & 63;
    const int w    = threadIdx.x >> 6;
    const int l16  = lane & 15;
    const int g    = lane >> 4;
    const int row0 = blockIdx.y * 128;
    const int col0 = blockIdx.x * 128;
    const int wr   = (w >> 1) * 64;
    const int wc   = (w & 1) * 64;

    // staging map: lane l of wave w -> tile row w*16 + l/4, swizzled 16B quad
    const int srow  = w * 16 + (lane >> 2);
    const int sswz8 = ((lane & 3) ^ ((lane >> 3) & 3)) * 8;   // source col swizzle
    const ushort* Ag = A  + (size_t)(row0 + srow) * K + sswz8;
    const ushort* Bg = Bt + (size_t)(col0 + srow) * K + sswz8;
    ushort* AsW = As + w * (16 * 32);
    ushort* BsW = Bs + w * (16 * 32);

    const int cq8 = (g ^ ((l16 >> 1) & 3)) * 8;               // read-side swizzle

    f32x4 acc[4][4] = {};

    for (int kk = 0; kk < K; kk += 32) {
        gload16(Ag + kk,          AsW);
        gload16(Ag + 64 * K + kk, AsW + 64 * 32);
        gload16(Bg + kk,          BsW);
        gload16(Bg + 64 * K + kk, BsW + 64 * 32);
        __syncthreads();                       // drains vmcnt(0) then s_barrier
        bf16x8 a[4], b[4];
        #pragma unroll
        for (int m = 0; m < 4; ++m)
            a[m] = *reinterpret_cast<const bf16x8*>(&As[(wr + m * 16 + l16) * 32 + cq8]);
        #pragma unroll
        for (int n = 0; n < 4; ++n)
            b[n] = *reinterpret_cast<const bf16x8*>(&Bs[(wc + n * 16 + l16) * 32 + cq8]);
        #pragma unroll
        for (int m = 0; m < 4; ++m)
            #pragma unroll
            for (int n = 0; n < 4; ++n)
                acc[m][n] = __builtin_amdgcn_mfma_f32_16x16x32_bf16(a[m], b[n], acc[m][n], 0, 0, 0);
        __syncthreads();                       // before next stage overwrites LDS
    }

    if (MODE == 0) {
        const int part = col0 >> 10;                    // 0=Q 1=K 2=V (uniform per block)
        const float QSC = 0.18033688011112042f;         // DIM_HEAD^-0.5 * log2(e)
        #pragma unroll
        for (int m = 0; m < 4; ++m) {
            const int trow = row0 + wr + m * 16 + 4 * g;
            #pragma unroll
            for (int n = 0; n < 4; ++n) {
                const int c  = col0 + wc + n * 16 + l16;
                const int cc = c & 1023;
                const int h  = cc >> 6, d = cc & 63;
                #pragma unroll
                for (int jj = 0; jj < 4; ++jj) {
                    const int t  = trow + jj;
                    const int bb = t >> 11, nn = t & 2047;
                    const float v = acc[m][n][jj];
                    const size_t bhid = (size_t)(bb * NHEAD + h);
                    if (part == 0)
                        Qb[(bhid * NSEQ + nn) * DHEAD + d] = f32_bf16(v * QSC);
                    else if (part == 1)
                        Kb[(bhid * NSEQ + nn) * DHEAD + d] = f32_bf16(v);
                    else  // V^T tiled: [bh][n/32][d:64][n%32]
                        Vtb[bhid * (NSEQ * DHEAD) + (size_t)(nn >> 5) * (DHEAD * 32)
                            + d * 32 + (nn & 31)] = f32_bf16(v);
                }
            }
        }
    } else {
        #pragma unroll
        for (int m = 0; m < 4; ++m) {
            const int trow = row0 + wr + m * 16 + 4 * g;
            #pragma unroll
            for (int n = 0; n < 4; ++n) {
                const int c = col0 + wc + n * 16 + l16;
                const float bv = bias[c];
                #pragma unroll
                for (int jj = 0; jj < 4; ++jj)
                    Out[(size_t)(trow + jj) * DMODEL + c] = acc[m][n][jj] + bv;
            }
        }
    }
}

// QK^T (swapped) + online softmax for one 16-row q-tile against a 64-key LDS
// tile. Lane(l16,g) holds S[key=16t+4g+jj][q=l16]. Permlane reductions;
// defer-rescale THR=8.
__device__ __forceinline__ void attn_qk(
    int kt, int qr0s, int l16, int g,
    const bf16x8 (&kk)[4][2],
    const bf16x8 qf0, const bf16x8 qf1,
    f32x4 (&oacc)[4], float& mrun, float& lsum,
    bf16x8& pf0, bf16x8& pf1)
{
    const f32x4 zero = {};
    f32x4 s[4];
    __builtin_amdgcn_s_setprio(1);
    #pragma unroll
    for (int t = 0; t < 4; ++t) {
        s[t] = __builtin_amdgcn_mfma_f32_16x16x32_bf16(kk[t][0], qf0, zero, 0, 0, 0);
        s[t] = __builtin_amdgcn_mfma_f32_16x16x32_bf16(kk[t][1], qf1, s[t], 0, 0, 0);
    }
    __builtin_amdgcn_s_setprio(0);
    if (kt + 63 > qr0s) {                               // diagonal tiles only
        const int kb = kt + 4 * g - (qr0s + l16);       // key - q = kb + 16t + jj
        #pragma unroll
        for (int t = 0; t < 4; ++t)
            #pragma unroll
            for (int jj = 0; jj < 4; ++jj)
                if (kb + 16 * t + jj > 0) s[t][jj] = -1e30f;
    }
    // in-lane max tree shaped for v_max3 fusion (16 values -> 8 ops)
    const float m0 = fmaxf(fmaxf(s[0][0], s[0][1]), s[0][2]);
    const float m1 = fmaxf(fmaxf(s[0][3], s[1][0]), s[1][1]);
    const float m2 = fmaxf(fmaxf(s[1][2], s[1][3]), s[2][0]);
    const float m3 = fmaxf(fmaxf(s[2][1], s[2][2]), s[2][3]);
    const float m4 = fmaxf(fmaxf(s[3][0], s[3][1]), s[3][2]);
    const float m5 = fmaxf(fmaxf(m0, m1), m2);
    const float m6 = fmaxf(fmaxf(m3, m4), s[3][3]);
    float mx = red_max_g(fmaxf(m5, m6));
    // defer-rescale: only when some row grew past mrun + 8
    if (__any(mx > mrun + 8.0f)) {
        const float mn = fmaxf(mrun, mx);
        const float sc = __builtin_amdgcn_exp2f(mrun - mn);
        mrun = mn;
        lsum *= sc;
        float scj[4];
        #pragma unroll
        for (int jj = 0; jj < 4; ++jj) scj[jj] = __shfl(sc, 4 * g + jj);
        #pragma unroll
        for (int dt = 0; dt < 4; ++dt)
            #pragma unroll
            for (int jj = 0; jj < 4; ++jj) oacc[dt][jj] *= scj[jj];
    }
    float ps = 0.f;
    unsigned int pw[4][2];
    #pragma unroll
    for (int t = 0; t < 4; ++t) {
        const float p0 = __builtin_amdgcn_exp2f(s[t][0] - mrun);
        const float p1 = __builtin_amdgcn_exp2f(s[t][1] - mrun);
        const float p2 = __builtin_amdgcn_exp2f(s[t][2] - mrun);
        const float p3 = __builtin_amdgcn_exp2f(s[t][3] - mrun);
        ps += (p0 + p1) + (p2 + p3);
        pw[t][0] = cvt_pk_bf16(p0, p1);
        pw[t][1] = cvt_pk_bf16(p2, p3);
    }
    lsum += red_sum_g(ps);
    // relayout to PV A-fragment via permlane32/16 swaps (distinct defs ->
    // no coalescing hazard)
    unsigned int a0 = pw[0][0], a1 = pw[0][1], b0 = pw[1][0], b1 = pw[1][1];
    permlane32_swap(a0, b0); permlane32_swap(a1, b1);
    permlane16_swap(a0, b0); permlane16_swap(a1, b1);
    pf0 = __builtin_bit_cast(bf16x8, (uint32x4){a0, a1, b0, b1});
    unsigned int c0 = pw[2][0], c1 = pw[2][1], d0 = pw[3][0], d1 = pw[3][1];
    permlane32_swap(c0, d0); permlane32_swap(c1, d1);
    permlane16_swap(c0, d0); permlane16_swap(c1, d1);
    pf1 = __builtin_bit_cast(bf16x8, (uint32x4){c0, c1, d0, d1});
}

// Causal flash attention. 1024 blocks (XCD-swizzled). 4 waves/block; each wave
// owns TWO 16-row q-tiles from complementary q-blocks {j, 31-j}. K/V 64-key
// tiles staged into double-buffered LDS via global_load_lds (swizzled source);
// 2-phase pipeline, 1 barrier/iter.
__global__ __launch_bounds__(256) void attn_kernel(
    const ushort* __restrict__ Qb, const ushort* __restrict__ Kb,
    const ushort* __restrict__ Vt, ushort* __restrict__ Ob)
{
    // K tile: [2 d-halves][64 keys][32 d]; V tile: [2 k-halves][64 d][32 k]
    __shared__ __align__(16) ushort Klds[2][4096];
    __shared__ __align__(16) ushort Vlds[2][4096];

    const int lane = threadIdx.x & 63;
    const int w    = threadIdx.x >> 6;
    const int l16  = lane & 15;
    const int g    = lane >> 4;

    const int bid = blockIdx.x;
    const int xcd = bid & 7, ii = bid >> 3;
    const int bh  = xcd * 8 + (ii >> 4);               // 8 (b,h) per XCD
    const int jlo = ii & 15;
    const int jhi = 31 - jlo;

    const int qr0_lo = jlo * 64 + w * 16;
    const int qr0_hi = jhi * 64 + w * 16;
    const int nt = jhi + 1;                            // 64-key tiles

    const ushort* QpL = Qb + ((size_t)bh * NSEQ + qr0_lo + l16) * DHEAD + 8 * g;
    const ushort* QpH = Qb + ((size_t)bh * NSEQ + qr0_hi + l16) * DHEAD + 8 * g;
    const bf16x8 qfL0 = *reinterpret_cast<const bf16x8*>(QpL);
    const bf16x8 qfL1 = *reinterpret_cast<const bf16x8*>(QpL + 32);
    const bf16x8 qfH0 = *reinterpret_cast<const bf16x8*>(QpH);
    const bf16x8 qfH1 = *reinterpret_cast<const bf16x8*>(QpH + 32);

    const ushort* Kg = Kb + (size_t)bh * (NSEQ * DHEAD);
    const ushort* Vg = Vt + (size_t)bh * (NSEQ * DHEAD);

    // staging: wave w, issue i in {0,1} -> 512-elem chunk q = w*2+i
    const int q0    = w * 2;
    const int srow  = lane >> 2;                              // row within 16-row chunk
    const int sswz8 = ((lane & 3) ^ ((lane >> 3) & 3)) * 8;   // swizzled source quad
    const int cq8   = (g ^ ((l16 >> 1) & 3)) * 8;             // read-side swizzle

    f32x4 oaccL[4] = {}, oaccH[4] = {};
    float mrunL = -1e30f, lsumL = 0.f, mrunH = -1e30f, lsumH = 0.f;

    // prologue: stage tile 0
    #pragma unroll
    for (int i = 0; i < 2; ++i) {
        const int q = q0 + i;
        gload16(Kg + (size_t)((q & 3) * 16 + srow) * 64 + (q >> 2) * 32 + sswz8,
                &Klds[0][q * 512]);
        gload16(Vg + (size_t)(q >> 2) * 2048 + ((q & 3) * 16 + srow) * 32 + sswz8,
                &Vlds[0][q * 512]);
    }
    __syncthreads();

    for (int t = 0; t < nt; ++t) {
        const int cur = t & 1;
        if (t + 1 < nt) {
            const int kt1 = (t + 1) * 64;
            #pragma unroll
            for (int i = 0; i < 2; ++i) {
                const int q = q0 + i;
                gload16(Kg + (size_t)(kt1 + (q & 3) * 16 + srow) * 64 + (q >> 2) * 32 + sswz8,
                        &Klds[cur ^ 1][q * 512]);
                gload16(Vg + (size_t)kt1 * 64 + (q >> 2) * 2048 + ((q & 3) * 16 + srow) * 32 + sswz8,
                        &Vlds[cur ^ 1][q * 512]);
            }
        }
        const int kt = t * 64;
        // K fragments from LDS (swizzled read)
        bf16x8 kk[4][2];
        #pragma unroll
        for (int tt = 0; tt < 4; ++tt) {
            #pragma unroll
            for (int h = 0; h < 2; ++h)
                kk[tt][h] = *reinterpret_cast<const bf16x8*>(
                    &Klds[cur][h * 2048 + (16 * tt + l16) * 32 + cq8]);
        }
        bf16x8 pfH0, pfH1, pfL0, pfL1;
        attn_qk(kt, qr0_hi, l16, g, kk, qfH0, qfH1, oaccH, mrunH, lsumH, pfH0, pfH1);
        const bool doLo = (t <= jlo);
        if (doLo)
            attn_qk(kt, qr0_lo, l16, g, kk, qfL0, qfL1, oaccL, mrunL, lsumL, pfL0, pfL1);
        // PV: V fragments from LDS (swizzled read), shared by hi/lo
        __builtin_amdgcn_s_setprio(1);
        #pragma unroll
        for (int dt = 0; dt < 4; ++dt) {
            const bf16x8 v0 = *reinterpret_cast<const bf16x8*>(
                &Vlds[cur][(dt * 16 + l16) * 32 + cq8]);
            const bf16x8 v1 = *reinterpret_cast<const bf16x8*>(
                &Vlds[cur][2048 + (dt * 16 + l16) * 32 + cq8]);
            oaccH[dt] = __builtin_amdgcn_mfma_f32_16x16x32_bf16(pfH0, v0, oaccH[dt], 0, 0, 0);
            oaccH[dt] = __builtin_amdgcn_mfma_f32_16x16x32_bf16(pfH1, v1, oaccH[dt], 0, 0, 0);
            if (doLo) {
                oaccL[dt] = __builtin_amdgcn_mfma_f32_16x16x32_bf16(pfL0, v0, oaccL[dt], 0, 0, 0);
                oaccL[dt] = __builtin_amdgcn_mfma_f32_16x16x32_bf16(pfL1, v1, oaccL[dt], 0, 0, 0);
            }
        }
        __builtin_amdgcn_s_setprio(0);
        __syncthreads();                               // drain stage + protect bufs
    }

    const int bb = bh >> 4, h = bh & 15;
    {
        const float inv = 1.0f / lsumH;
        float invj[4];
        #pragma unroll
        for (int jj = 0; jj < 4; ++jj) invj[jj] = __shfl(inv, 4 * g + jj);
        #pragma unroll
        for (int jj = 0; jj < 4; ++jj) {
            const size_t t = (size_t)bb * NSEQ + qr0_hi + 4 * g + jj;
            #pragma unroll
            for (int dt = 0; dt < 4; ++dt)
                Ob[t * DMODEL + h * DHEAD + dt * 16 + l16] = f32_bf16(oaccH[dt][jj] * invj[jj]);
        }
    }
    {
        const float inv = 1.0f / lsumL;
        float invj[4];
        #pragma unroll
        for (int jj = 0; jj < 4; ++jj) invj[jj] = __shfl(inv, 4 * g + jj);
        #pragma unroll
        for (int jj = 0; jj < 4; ++jj) {
            const size_t t = (size_t)bb * NSEQ + qr0_lo + 4 * g + jj;
            #pragma unroll
            for (int dt = 0; dt < 4; ++dt)
                Ob[t * DMODEL + h * DHEAD + dt * 16 + l16] = f32_bf16(oaccL[dt][jj] * invj[jj]);
        }
    }
}

extern "C" void kernel_launch(void* const* d_in, const int* in_sizes, int n_in,
                              void* d_out, int out_size, void* d_ws, size_t ws_size,
                              hipStream_t stream)
{
    const float* x     = (const float*)d_in[0];
    const float* w_qkv = (const float*)d_in[1];
    const float* w_out = (const float*)d_in[2];
    const float* b_out = (const float*)d_in[3];
    float* out = (float*)d_out;

    char* ws = (char*)d_ws;
    // workspace layout (bytes); total 75,497,472
    ushort* x_bf   = (ushort*)(ws);                    // 16,777,216  (reused as attn out)
    ushort* wqkv_t = (ushort*)(ws + 16777216);         //  6,291,456
    ushort* wout_t = (ushort*)(ws + 23068672);         //  2,097,152
    ushort* q_bf   = (ushort*)(ws + 25165824);         // 16,777,216
    ushort* k_bf   = (ushort*)(ws + 41943040);         // 16,777,216
    ushort* vt_bf  = (ushort*)(ws + 58720256);         // 16,777,216 (V^T tiled)
    ushort* attn_bf = x_bf;                            // alias: x_bf dead after QKV GEMM

    cvt_x_kernel<<<dim3(TOKENS * DMODEL / 4 / 256), dim3(256), 0, stream>>>(x, x_bf);
    cvt_wt_kernel<<<dim3(NQKV / 64, 1024 / 64), dim3(256), 0, stream>>>(w_qkv, wqkv_t, NQKV);
    cvt_wt_kernel<<<dim3(1024 / 64, 1024 / 64), dim3(256), 0, stream>>>(w_out, wout_t, 1024);

    gemm_bt<0><<<dim3(NQKV / 128, TOKENS / 128), dim3(256), 0, stream>>>(
        x_bf, wqkv_t, q_bf, k_bf, vt_bf, nullptr, nullptr);

    attn_kernel<<<dim3(1024), dim3(256), 0, stream>>>(q_bf, k_bf, vt_bf, attn_bf);

    gemm_bt<1><<<dim3(DMODEL / 128, TOKENS / 128), dim3(256), 0, stream>>>(
        attn_bf, wout_t, nullptr, nullptr, nullptr, out, b_out);
}